// Round 7
// baseline (407.525 us; speedup 1.0000x reference)
//
#include <hip/hip_runtime.h>

typedef unsigned short u16;
typedef unsigned int u32;
typedef __attribute__((ext_vector_type(8))) short short8;
typedef __attribute__((ext_vector_type(4))) float f32x4;

__device__ __forceinline__ float bf2f(u16 u){ union { u32 i; float f; } x; x.i = ((u32)u)<<16; return x.f; }
__device__ __forceinline__ u16 f2bf(float f){ union { float f; u32 i; } x; x.f = f; u32 r = x.i + 0x7fffu + ((x.i>>16)&1u); return (u16)(r>>16); }

#define MFMA16(a,b,c) __builtin_amdgcn_mfma_f32_16x16x32_bf16((a),(b),(c),0,0,0)

// ---- dual-dtype external loads: fp32 inputs are converted to bf16 at ingest ----
__device__ __forceinline__ uint4 ld8(const void* p, size_t off, int f32) {
  if (f32) {
    const float* fp = (const float*)p + off;
    float4 a = *(const float4*)fp;
    float4 b = *(const float4*)(fp + 4);
    uint4 o;
    o.x = (u32)f2bf(a.x) | ((u32)f2bf(a.y)<<16);
    o.y = (u32)f2bf(a.z) | ((u32)f2bf(a.w)<<16);
    o.z = (u32)f2bf(b.x) | ((u32)f2bf(b.y)<<16);
    o.w = (u32)f2bf(b.z) | ((u32)f2bf(b.w)<<16);
    return o;
  }
  return *(const uint4*)((const u16*)p + off);
}
__device__ __forceinline__ uint2 ld4(const void* p, size_t off, int f32) {
  if (f32) {
    const float* fp = (const float*)p + off;
    float4 a = *(const float4*)fp;
    uint2 o;
    o.x = (u32)f2bf(a.x) | ((u32)f2bf(a.y)<<16);
    o.y = (u32)f2bf(a.z) | ((u32)f2bf(a.w)<<16);
    return o;
  }
  return *(const uint2*)((const u16*)p + off);
}
__device__ __forceinline__ float ldsc(const void* p, size_t off, int f32) {
  if (f32) return ((const float*)p)[off];
  return bf2f(((const u16*)p)[off]);
}

// ---- K-1: detect input dtype from x's low 16 bits (bf16 exponent vs fp32 mantissa) ----
__global__ __launch_bounds__(256) void k_detect(const u32* __restrict__ x, int* __restrict__ flag)
{
  __shared__ int cnt;
  if (threadIdx.x == 0) cnt = 0;
  __syncthreads();
  int c = 0;
  #pragma unroll
  for (int i = 0; i < 32; ++i) {
    u32 w = x[threadIdx.x*32 + i];
    u32 e = (w >> 7) & 0xFFu;
    c += (e == 0u || (e >= 96u && e <= 143u)) ? 1 : 0;
  }
  atomicAdd(&cnt, c);
  __syncthreads();
  if (threadIdx.x == 0) *flag = (cnt < 4915) ? 1 : 0;
}

// ---- K-fuse: W_fused = wconv @ wo (bf16), b_fused = wconv @ bo + bconv (f32).
// Also performs dtype detection per-WG (local vote over x[0:2048]) and WG(0,0)
// publishes the flag for downstream kernels.
__global__ __launch_bounds__(256) void k_fuse_w(
  const u32* __restrict__ x,
  const void* __restrict__ wo, const void* __restrict__ wconv,
  const void* __restrict__ bo, const void* __restrict__ bconv,
  u16* __restrict__ F, float* __restrict__ bfus, int* __restrict__ flagp)
{
  __shared__ int cnt;
  __shared__ __align__(16) u16 WC[16*256];   // wconv o-block, bf16
  __shared__ __align__(16) u16 WO[32*128];   // wo j-chunk x c-half, bf16
  __shared__ float bred[16][17];
  const int t = threadIdx.x;
  if (t == 0) cnt = 0;
  __syncthreads();
  {
    int c = 0;
    #pragma unroll
    for (int i=0;i<8;++i) {
      u32 w = x[t*8+i];
      u32 e = (w>>7)&0xFFu;
      c += (e==0u || (e>=96u && e<=143u)) ? 1 : 0;
    }
    atomicAdd(&cnt, c);
  }
  __syncthreads();
  const int f32 = (cnt < 1229) ? 1 : 0;     // 2048 words: bf16 ~2048, fp32 ~390
  if (blockIdx.x == 0 && blockIdx.y == 0 && t == 0) *flagp = f32;
  const int o0 = blockIdx.x*16, c0 = blockIdx.y*128;
  {
    int row = t>>4, ch = (t&15)*16;
    *(uint4*)&WC[row*256+ch]     = ld8(wconv, (size_t)(o0+row)*256 + ch, f32);
    *(uint4*)&WC[row*256+ch+8]   = ld8(wconv, (size_t)(o0+row)*256 + ch + 8, f32);
  }
  float acc[8] = {};
  const int ty = t>>4, tx = t&15;
  for (int jc=0;jc<8;++jc) {
    __syncthreads();    // (jc=0: also covers WC staging) protect WO reuse
    {
      int jr = t>>3, cc = (t&7)*16;
      *(uint4*)&WO[jr*128+cc]   = ld8(wo, (size_t)(jc*32+jr)*256 + c0 + cc, f32);
      *(uint4*)&WO[jr*128+cc+8] = ld8(wo, (size_t)(jc*32+jr)*256 + c0 + cc + 8, f32);
    }
    __syncthreads();
    #pragma unroll 4
    for (int jj=0;jj<32;++jj) {
      float wv = bf2f(WC[ty*256 + jc*32 + jj]);
      short8 w8 = *(const short8*)&WO[jj*128 + tx*8];
      #pragma unroll
      for (int i=0;i<8;++i) acc[i] += wv * bf2f((u16)w8[i]);
    }
  }
  {
    u32 pw[4];
    #pragma unroll
    for (int j=0;j<4;++j) pw[j] = (u32)f2bf(acc[2*j]) | ((u32)f2bf(acc[2*j+1])<<16);
    *(uint4*)&F[(size_t)(o0+ty)*256 + c0 + tx*8] = *(uint4*)pw;
  }
  // parallel bias: b_fused[o] = sum_j wconv[o][j]*bo[j] + bconv[o]   (WC still resident)
  if (blockIdx.y == 0) {
    float s = 0.0f;
    #pragma unroll 4
    for (int j=tx*16; j<tx*16+16; ++j) s += bf2f(WC[ty*256+j]) * ldsc(bo, j, f32);
    bred[ty][tx] = s;
  }
  __syncthreads();
  if (blockIdx.y == 0 && t < 16) {
    float s = 0.0f;
    #pragma unroll
    for (int p=0;p<16;++p) s += bred[t][p];
    bfus[o0+t] = s + ldsc(bconv, o0+t, f32);
  }
}

// ---------------- K0: transpose x (B,C,HW) -> xt (B*HW, C), bf16 ----------------
__global__ __launch_bounds__(256) void k_transpose(const void* __restrict__ x, u16* __restrict__ xt,
                                                   const int* __restrict__ flagp)
{
  __shared__ int sflag;
  __shared__ __align__(16) u16 tile[64][68];
  if (threadIdx.x == 0) sflag = *flagp;
  __syncthreads();
  const int f32 = sflag;
  const int p0 = blockIdx.x*64, c0 = blockIdx.y*64, b = blockIdx.z;
  const int t = threadIdx.x;
  const size_t xbo = ((size_t)(b*256 + c0))*4096 + p0;
  #pragma unroll
  for (int pass=0; pass<4; ++pass) {
    int cl = pass*16 + (t>>4);
    int pl = (t&15)*4;
    uint2 v = ld4(x, xbo + (size_t)cl*4096 + pl, f32);
    *(uint2*)&tile[cl][pl] = v;
  }
  __syncthreads();
  u16* xtb = xt + ((size_t)b*4096 + p0)*256 + c0;
  #pragma unroll
  for (int pass=0; pass<4; ++pass) {
    int pl = pass*16 + (t>>4);
    int cl = (t&15)*4;
    unsigned int lo = (unsigned int)tile[cl][pl]   | ((unsigned int)tile[cl+1][pl]<<16);
    unsigned int hi = (unsigned int)tile[cl+2][pl] | ((unsigned int)tile[cl+3][pl]<<16);
    uint2 o; o.x = lo; o.y = hi;
    *(uint2*)(xtb + (size_t)pl*256 + cl) = o;
  }
}

// ------------- generic GEMM: C[M,N] = A[M,K] @ Bt[N,K]^T * colscale + bias --------------
// NO-LDS main loop: each lane loads its MFMA fragments DIRECTLY from global
// (16B/lane, 64B segments per 16 lanes; A rows and the small B panel are L1/L2
// resident). No staging, no ds ops, no barriers in the K-loop — TLP hides L2
// latency. LDS is only the 18.4KB epilogue scratch.
// B split-routed (128-aligned nsplit). internalB=1: Bt/bias internal (bf16/f32).
// shuffle=1: PixelShuffle(2) epilogue, 4 chunks of 32 cols, ef stride 134
// (bank = 24cn+8lq+6rr+ss -> uniform 4-way instead of ~6.4-way).
__global__ __launch_bounds__(256) void k_gemm_bt(
  const u16* __restrict__ A, int lda,
  const void* __restrict__ Bt0, const void* __restrict__ Bt1, int nsplit,
  const void* __restrict__ bias,
  void* __restrict__ C, int M, int N, int K,
  float s_lo, float s_hi, int shuffle, int internalB,
  const int* __restrict__ flagp)
{
  __shared__ int sflag;
  __shared__ __align__(16) char smem[18432];
  if (threadIdx.x == 0) sflag = *flagp;
  __syncthreads();
  const int f32 = sflag;
  const int bf = internalB ? 0 : f32;          // dtype of Bt loads
  const int biasf = internalB ? 1 : f32;       // dtype of bias loads
  const int m0 = blockIdx.x*128, n0 = blockIdx.y*128;
  const void* Bs; int boff;
  if (Bt1 && n0 >= nsplit) { Bs = Bt1; boff = n0 - nsplit; } else { Bs = Bt0; boff = n0; }
  const int t = threadIdx.x, lane = t & 63, wv = t >> 6;
  const int wm = (wv & 1)*64, wn = (wv >> 1)*64;
  const int lm = lane & 15, lq = lane >> 4;
  f32x4 acc[4][4] = {};

  // per-lane fragment base offsets
  const u16* arow[4];
  size_t brow[4];
  #pragma unroll
  for (int i=0;i<4;++i) {
    arow[i] = A + (size_t)(m0 + wm + i*16 + lm)*lda + lq*8;
    brow[i] = (size_t)(boff + wn + i*16 + lm)*K + lq*8;
  }

  #pragma unroll 2
  for (int k0 = 0; k0 < K; k0 += 32) {
    short8 af[4], bfr[4];
    #pragma unroll
    for (int i=0;i<4;++i) af[i] = *(const short8*)(arow[i] + k0);
    #pragma unroll
    for (int i=0;i<4;++i) { uint4 v = ld8(Bs, brow[i] + k0, bf); bfr[i] = *(const short8*)&v; }
    #pragma unroll
    for (int mt=0;mt<4;++mt)
      #pragma unroll
      for (int nt=0;nt<4;++nt)
        acc[mt][nt] = MFMA16(af[mt], bfr[nt], acc[mt][nt]);
  }

  if (!shuffle) {
    u16* eh = (u16*)smem;   // 128 x 72 u16 (18432B)
    #pragma unroll
    for (int c=0;c<2;++c) {
      __syncthreads();
      if ((wv>>1) == c) {
        #pragma unroll
        for (int nt=0;nt<4;++nt) {
          int col = n0 + c*64 + nt*16 + lm;
          float sc = (col < nsplit) ? s_lo : s_hi;
          float bv = bias ? ldsc(bias, col, biasf) : 0.0f;
          #pragma unroll
          for (int mt=0;mt<4;++mt)
            #pragma unroll
            for (int r=0;r<4;++r) {
              int row = wm + mt*16 + lq*4 + r;
              eh[row*72 + nt*16 + lm] = f2bf(acc[mt][nt][r]*sc + bv);
            }
        }
      }
      __syncthreads();
      {
        int row = t >> 1, off = (t & 1)*32;
        const uint4* s = (const uint4*)&eh[row*72 + off];
        uint4 v0 = s[0], v1 = s[1], v2 = s[2], v3 = s[3];
        uint4* dp = (uint4*)((u16*)C + (size_t)(m0+row)*N + n0 + c*64 + off);
        dp[0]=v0; dp[1]=v1; dp[2]=v2; dp[3]=v3;
      }
    }
  } else {
    // 4 chunks of 32 cols; ef = 32 output-rows x 134 fp32 (17152B)
    float* ef = (float*)smem;
    const int b = m0 >> 12;
    const int hh0 = (m0 & 4095) >> 6;   // tile = 2 image rows (hh0, hh0+1) x 64 px
    #pragma unroll
    for (int c=0;c<4;++c) {
      __syncthreads();
      if ((wv>>1) == (c>>1)) {
        #pragma unroll
        for (int nt2=0;nt2<2;++nt2) {
          int nt = (c&1)*2 + nt2;
          int col = n0 + wn + nt*16 + lm;             // global col
          float bv = bias ? ldsc(bias, col, biasf) : 0.0f;
          int col_rel = nt2*16 + lm;                  // 0..31 within chunk
          int cn_rel = col_rel >> 2, rr = (col_rel >> 1) & 1, ss = col_rel & 1;
          #pragma unroll
          for (int mt=0;mt<4;++mt)
            #pragma unroll
            for (int r=0;r<4;++r) {
              int row = wm + mt*16 + lq*4 + r;        // 0..127 (pixel within tile)
              int orow = cn_rel*4 + (row>>6)*2 + rr;  // output-row within chunk (0..31)
              int ow   = (row & 63)*2 + ss;           // 0..127
              ef[orow*134 + ow] = acc[mt][nt][r]*s_hi + bv;
            }
        }
      }
      __syncthreads();
      {
        int orow = t >> 3, seg = t & 7;               // 8 lanes cover one full 512B row
        int cn_rel = orow >> 2, oh_rel = orow & 3;
        int cn = ((n0 + c*32) >> 2) + cn_rel;
        size_t obase = (((size_t)(b*256 + cn))*128 + hh0*2 + oh_rel)*128 + seg*16;
        const float4* s = (const float4*)&ef[orow*134 + seg*16];
        float4 v0 = s[0], v1 = s[1], v2 = s[2], v3 = s[3];
        if (f32) {
          float4* dp = (float4*)((float*)C + obase);
          dp[0]=v0; dp[1]=v1; dp[2]=v2; dp[3]=v3;
        } else {
          float vv[16];
          *(float4*)&vv[0]=v0; *(float4*)&vv[4]=v1; *(float4*)&vv[8]=v2; *(float4*)&vv[12]=v3;
          u32 pw[8];
          #pragma unroll
          for (int j=0;j<8;++j) pw[j] = (u32)f2bf(vv[2*j]) | ((u32)f2bf(vv[2*j+1])<<16);
          u16* dp = (u16*)C + obase;
          *(uint4*)dp       = *(uint4*)&pw[0];
          *(uint4*)(dp + 8) = *(uint4*)&pw[4];
        }
      }
    }
  }
}

// ---------------- K2: halo attention, one WG per (block, head) ----------------
// Reads fused qkv buffer (stride 768: q | k | v); writes output to
// aout[p*ostride + head*64 + d] (ostride=256 for separate arena, 768 for in-place).
#define MASKVAL (-30000.0f)
__global__ __launch_bounds__(256) void k_halo_attn(
  const u16* __restrict__ qkv,
  const void* __restrict__ relh, const void* __restrict__ relw,
  u16* __restrict__ aout, int ostride,
  const int* __restrict__ flagp)
{
  __shared__ int sflag;
  __shared__ __align__(16) u16 Qs[64*72];
  __shared__ __align__(16) u16 KP[128*72];
  __shared__ __align__(16) u16 Vt[64*136];
  __shared__ __align__(16) u16 Gw[64*32];
  __shared__ __align__(16) u16 Gh[64*32];
  if (threadIdx.x == 0) sflag = *flagp;
  __syncthreads();
  const int f32 = sflag;

  const int blk = blockIdx.x, head = blockIdx.y;
  const int bb = blk >> 6, by = (blk >> 3) & 7, bx = blk & 7;
  const int h0 = by*8, w0 = bx*8;
  const int t = threadIdx.x, lane = t & 63, wv = t >> 6;
  const int lm = lane & 15, lq = lane >> 4;
  const size_t pixbase = (size_t)bb * 4096;
  const float LOG2E = 1.4426950408889634f;

  #pragma unroll
  for (int i=0;i<2;++i) {
    int u = t + i*256;
    int row = u >> 3, ch = (u & 7)*8;
    int qx = row >> 3, qy = row & 7;
    size_t p = pixbase + (size_t)(h0+qx)*64 + (w0+qy);
    *(uint4*)&Qs[row*72 + ch] = *(const uint4*)(qkv + p*768 + head*64 + ch);
  }
  {
    u16* RW = KP; u16* RH = KP + 2048;
    if (t < 248) {
      *(uint4*)&RW[t*8] = ld8(relw, (size_t)t*8, f32);
      *(uint4*)&RH[t*8] = ld8(relh, (size_t)t*8, f32);
    } else {
      uint4 z; z.x=z.y=z.z=z.w=0;
      int o = 1984 + (t-248)*8;
      *(uint4*)&RW[o] = z;
      *(uint4*)&RH[o] = z;
    }
  }
  __syncthreads();
  {
    const u16* RW = KP; const u16* RH = KP + 2048;
    f32x4 agw[2] = {}, agh[2] = {};
    #pragma unroll
    for (int ks=0;ks<2;++ks) {
      short8 aq = *(const short8*)&Qs[(wv*16 + lm)*72 + ks*32 + lq*8];
      #pragma unroll
      for (int nt=0;nt<2;++nt) {
        short8 bw = *(const short8*)&RW[(nt*16 + lm)*64 + ks*32 + lq*8];
        short8 bh = *(const short8*)&RH[(nt*16 + lm)*64 + ks*32 + lq*8];
        agw[nt] = MFMA16(aq, bw, agw[nt]);
        agh[nt] = MFMA16(aq, bh, agh[nt]);
      }
    }
    #pragma unroll
    for (int nt=0;nt<2;++nt)
      #pragma unroll
      for (int r=0;r<4;++r) {
        int m = wv*16 + lq*4 + r, c = nt*16 + lm;
        Gw[m*32 + c] = f2bf(agw[nt][r]);
        Gh[m*32 + c] = f2bf(agh[nt][r]);
      }
  }
  __syncthreads();

  float m_run[4], l_run[4];
  #pragma unroll
  for (int r=0;r<4;++r){ m_run[r] = MASKVAL; l_run[r] = 0.0f; }
  f32x4 acc_o[4] = {};

  for (int tile=0; tile<2; ++tile) {
    #pragma unroll
    for (int i=0;i<4;++i) {
      int u = t + i*256;
      int kl = u >> 3, ch = (u & 7)*8;
      int ki = tile*8 + (kl >> 4), kj = kl & 15;
      int hk = h0 - 4 + ki, wk = w0 - 4 + kj;
      uint4 v; v.x=v.y=v.z=v.w=0;
      if ((unsigned)hk < 64u && (unsigned)wk < 64u) {
        size_t p = pixbase + (size_t)hk*64 + wk;
        v = *(const uint4*)(qkv + p*768 + 256 + head*64 + ch);
      }
      *(uint4*)&KP[kl*72 + ch] = v;
    }
    {
      int kl = t & 127, db = (t >> 7)*32;
      int ki = tile*8 + (kl >> 4), kj = kl & 15;
      int hk = h0 - 4 + ki, wk = w0 - 4 + kj;
      bool ok = ((unsigned)hk < 64u) && ((unsigned)wk < 64u);
      size_t p = pixbase + (size_t)hk*64 + wk;
      const u16* vp = qkv + p*768 + 512 + head*64 + db;
      #pragma unroll
      for (int c=0;c<4;++c) {
        union { uint4 v; u16 s[8]; } uu;
        uu.v.x=uu.v.y=uu.v.z=uu.v.w=0;
        if (ok) uu.v = *(const uint4*)(vp + c*8);
        #pragma unroll
        for (int jj=0;jj<8;++jj) Vt[(db + c*8 + jj)*136 + kl] = uu.s[jj];
      }
    }
    __syncthreads();
    f32x4 as[8] = {};
    #pragma unroll
    for (int ks=0;ks<2;++ks) {
      short8 aq = *(const short8*)&Qs[(wv*16 + lm)*72 + ks*32 + lq*8];
      #pragma unroll
      for (int nt=0;nt<8;++nt) {
        short8 bk = *(const short8*)&KP[(nt*16 + lm)*72 + ks*32 + lq*8];
        as[nt] = MFMA16(aq, bk, as[nt]);
      }
    }
    __syncthreads();
    #pragma unroll
    for (int r=0;r<4;++r) {
      int m = wv*16 + lq*4 + r;
      int qx = m >> 3, qy = m & 7;
      float vals[8]; float rowmax = MASKVAL;
      #pragma unroll
      for (int nt=0;nt<8;++nt) {
        int ki = tile*8 + nt;
        int hk = h0 - 4 + ki, wk = w0 - 4 + lm;
        float v = as[nt][r]
                + bf2f(Gw[m*32 + (lm - qy + 15)])
                + bf2f(Gh[m*32 + (ki - qx + 15)]);
        if (!((unsigned)hk < 64u && (unsigned)wk < 64u)) v = MASKVAL;
        vals[nt] = v;
        rowmax = fmaxf(rowmax, v);
      }
      #pragma unroll
      for (int s=1;s<16;s<<=1) rowmax = fmaxf(rowmax, __shfl_xor(rowmax, s, 64));
      float mnew = fmaxf(m_run[r], rowmax);
      float alpha = exp2f((m_run[r] - mnew)*LOG2E);
      float rs = 0.0f;
      #pragma unroll
      for (int nt=0;nt<8;++nt) {
        float e = exp2f((vals[nt] - mnew)*LOG2E);
        rs += e;
        KP[m*136 + nt*16 + lm] = f2bf(e);
      }
      #pragma unroll
      for (int s=1;s<16;s<<=1) rs += __shfl_xor(rs, s, 64);
      l_run[r] = l_run[r]*alpha + rs;
      m_run[r] = mnew;
      #pragma unroll
      for (int nt=0;nt<4;++nt) acc_o[nt][r] *= alpha;
    }
    __syncthreads();
    #pragma unroll
    for (int ks=0;ks<4;++ks) {
      short8 ap = *(const short8*)&KP[(wv*16 + lm)*136 + ks*32 + lq*8];
      #pragma unroll
      for (int nt=0;nt<4;++nt) {
        short8 bv = *(const short8*)&Vt[(nt*16 + lm)*136 + ks*32 + lq*8];
        acc_o[nt] = MFMA16(ap, bv, acc_o[nt]);
      }
    }
    __syncthreads();
  }
  #pragma unroll
  for (int nt=0;nt<4;++nt)
    #pragma unroll
    for (int r=0;r<4;++r) {
      int m = wv*16 + lq*4 + r;
      int qx = m >> 3, qy = m & 7;
      size_t p = pixbase + (size_t)(h0+qx)*64 + (w0+qy);
      aout[p*(size_t)ostride + head*64 + nt*16 + lm] = f2bf(acc_o[nt][r]/l_run[r]);
    }
}

extern "C" void kernel_launch(void* const* d_in, const int* in_sizes, int n_in,
                              void* d_out, int out_size, void* d_ws, size_t ws_size,
                              hipStream_t stream)
{
  const void* x     = d_in[0];
  const void* wq    = d_in[1];
  const void* wkv   = d_in[2];
  const void* wo    = d_in[3];
  const void* bo    = d_in[4];
  const void* relh  = d_in[5];
  const void* relw  = d_in[6];
  const void* wconv = d_in[7];
  const void* bconv = d_in[8];

  int*  flag = (int*)d_ws;
  u16*  base = (u16*)d_out;
  u16*  qkv  = base;                            // 32768 x 768 bf16 (q | k | v)
  u16*  xt   = base + 25165824;                 // 32768 x 256 bf16

  const size_t WS_FUSED = 4096 + 524288 + 4096 + 16777216;  // flag|Wf|bf|aout

  if (ws_size >= WS_FUSED) {
    // ---- fused path: wo-projection folded into the conv weights ----
    u16*   Wf   = (u16*)((char*)d_ws + 4096);
    float* bfus = (float*)((char*)d_ws + 4096 + 524288);
    u16*   aout = (u16*)((char*)d_ws + 4096 + 524288 + 4096);
    k_fuse_w<<<dim3(64,2), 256, 0, stream>>>((const u32*)x, wo, wconv, bo, bconv,
                                             Wf, bfus, flag);
    k_transpose<<<dim3(64,4,8), 256, 0, stream>>>(x, xt, flag);
    k_gemm_bt<<<dim3(256,6), 256, 0, stream>>>(xt, 256, wq, wkv, 256, nullptr,
                                               qkv, 32768, 768, 256, 0.125f, 1.0f, 0, 0, flag);
    k_halo_attn<<<dim3(512,4), 256, 0, stream>>>(qkv, relh, relw, aout, 256, flag);
    k_gemm_bt<<<dim3(256,8), 256, 0, stream>>>(aout, 256, Wf, nullptr, 0, bfus,
                                               d_out, 32768, 1024, 256, 1.0f, 1.0f, 1, 1, flag);
  } else {
    // ---- fallback (r2 pipeline): separate wo-GEMM through y2 in ws ----
    u16* y2 = (u16*)((char*)d_ws + 4096);
    k_detect<<<1, 256, 0, stream>>>((const u32*)x, flag);
    k_transpose<<<dim3(64,4,8), 256, 0, stream>>>(x, xt, flag);
    k_gemm_bt<<<dim3(256,6), 256, 0, stream>>>(xt, 256, wq, wkv, 256, nullptr,
                                               qkv, 32768, 768, 256, 0.125f, 1.0f, 0, 0, flag);
    k_halo_attn<<<dim3(512,4), 256, 0, stream>>>(qkv, relh, relw, qkv, 768, flag);
    k_gemm_bt<<<dim3(256,2), 256, 0, stream>>>(qkv, 768, wo, nullptr, 0, bo,
                                               y2, 32768, 256, 256, 1.0f, 1.0f, 0, 0, flag);
    k_gemm_bt<<<dim3(256,8), 256, 0, stream>>>(y2, 256, wconv, nullptr, 0, bconv,
                                               d_out, 32768, 1024, 256, 1.0f, 1.0f, 1, 0, flag);
  }
}

// Round 8
// 367.782 us; speedup vs baseline: 1.1081x; 1.1081x over previous
//
#include <hip/hip_runtime.h>

typedef unsigned short u16;
typedef unsigned int u32;
typedef __attribute__((ext_vector_type(8))) short short8;
typedef __attribute__((ext_vector_type(4))) float f32x4;

__device__ __forceinline__ float bf2f(u16 u){ union { u32 i; float f; } x; x.i = ((u32)u)<<16; return x.f; }
__device__ __forceinline__ u16 f2bf(float f){ union { float f; u32 i; } x; x.f = f; u32 r = x.i + 0x7fffu + ((x.i>>16)&1u); return (u16)(r>>16); }

#define MFMA16(a,b,c) __builtin_amdgcn_mfma_f32_16x16x32_bf16((a),(b),(c),0,0,0)

// ---- dual-dtype external loads: fp32 inputs are converted to bf16 at ingest ----
__device__ __forceinline__ uint4 ld8(const void* p, size_t off, int f32) {
  if (f32) {
    const float* fp = (const float*)p + off;
    float4 a = *(const float4*)fp;
    float4 b = *(const float4*)(fp + 4);
    uint4 o;
    o.x = (u32)f2bf(a.x) | ((u32)f2bf(a.y)<<16);
    o.y = (u32)f2bf(a.z) | ((u32)f2bf(a.w)<<16);
    o.z = (u32)f2bf(b.x) | ((u32)f2bf(b.y)<<16);
    o.w = (u32)f2bf(b.z) | ((u32)f2bf(b.w)<<16);
    return o;
  }
  return *(const uint4*)((const u16*)p + off);
}
__device__ __forceinline__ uint2 ld4(const void* p, size_t off, int f32) {
  if (f32) {
    const float* fp = (const float*)p + off;
    float4 a = *(const float4*)fp;
    uint2 o;
    o.x = (u32)f2bf(a.x) | ((u32)f2bf(a.y)<<16);
    o.y = (u32)f2bf(a.z) | ((u32)f2bf(a.w)<<16);
    return o;
  }
  return *(const uint2*)((const u16*)p + off);
}
__device__ __forceinline__ float ldsc(const void* p, size_t off, int f32) {
  if (f32) return ((const float*)p)[off];
  return bf2f(((const u16*)p)[off]);
}

// ---- K-1: detect input dtype from x's low 16 bits (bf16 exponent vs fp32 mantissa) ----
__global__ __launch_bounds__(256) void k_detect(const u32* __restrict__ x, int* __restrict__ flag)
{
  __shared__ int cnt;
  if (threadIdx.x == 0) cnt = 0;
  __syncthreads();
  int c = 0;
  #pragma unroll
  for (int i = 0; i < 32; ++i) {
    u32 w = x[threadIdx.x*32 + i];
    u32 e = (w >> 7) & 0xFFu;
    c += (e == 0u || (e >= 96u && e <= 143u)) ? 1 : 0;
  }
  atomicAdd(&cnt, c);
  __syncthreads();
  if (threadIdx.x == 0) *flag = (cnt < 4915) ? 1 : 0;
}

// ---- K-fuse: y=0,1: W_fused = wconv @ wo (bf16) + b_fused; y=2: convert wq|wkv
// to bf16 arena Wqkv[768][256]. All WGs do a local dtype vote; WG(0,0) publishes.
__global__ __launch_bounds__(256) void k_fuse_w(
  const u32* __restrict__ x,
  const void* __restrict__ wq, const void* __restrict__ wkv,
  const void* __restrict__ wo, const void* __restrict__ wconv,
  const void* __restrict__ bo, const void* __restrict__ bconv,
  u16* __restrict__ F, float* __restrict__ bfus, u16* __restrict__ Wqkv,
  int* __restrict__ flagp)
{
  __shared__ int cnt;
  __shared__ __align__(16) u16 WC[16*256];   // wconv o-block, bf16
  __shared__ __align__(16) u16 WO[32*128];   // wo j-chunk x c-half, bf16
  __shared__ float bred[16][17];
  const int t = threadIdx.x;
  if (t == 0) cnt = 0;
  __syncthreads();
  {
    int c = 0;
    #pragma unroll
    for (int i=0;i<8;++i) {
      u32 w = x[t*8+i];
      u32 e = (w>>7)&0xFFu;
      c += (e==0u || (e>=96u && e<=143u)) ? 1 : 0;
    }
    atomicAdd(&cnt, c);
  }
  __syncthreads();
  const int f32 = (cnt < 1229) ? 1 : 0;     // 2048 words: bf16 ~2048, fp32 ~390
  if (blockIdx.x == 0 && blockIdx.y == 0 && t == 0) *flagp = f32;

  if (blockIdx.y == 2) {
    // convert wq (rows 0..255) | wkv (rows 256..767) -> Wqkv bf16
    int rbase = blockIdx.x * 12;            // 64 WGs x 12 rows = 768
    #pragma unroll
    for (int p=0;p<2;++p) {
      int rr = p*8 + (t>>5);                // 0..15
      int cg = (t&31)*8;                    // 0..248
      if (rr < 12) {
        int row = rbase + rr;
        uint4 w = (row < 256) ? ld8(wq, (size_t)row*256 + cg, f32)
                              : ld8(wkv, (size_t)(row-256)*256 + cg, f32);
        *(uint4*)&Wqkv[(size_t)row*256 + cg] = w;
      }
    }
    return;
  }

  const int o0 = blockIdx.x*16, c0 = blockIdx.y*128;
  {
    int row = t>>4, ch = (t&15)*16;
    *(uint4*)&WC[row*256+ch]     = ld8(wconv, (size_t)(o0+row)*256 + ch, f32);
    *(uint4*)&WC[row*256+ch+8]   = ld8(wconv, (size_t)(o0+row)*256 + ch + 8, f32);
  }
  float acc[8] = {};
  const int ty = t>>4, tx = t&15;
  for (int jc=0;jc<8;++jc) {
    __syncthreads();    // (jc=0: also covers WC staging) protect WO reuse
    {
      int jr = t>>3, cc = (t&7)*16;
      *(uint4*)&WO[jr*128+cc]   = ld8(wo, (size_t)(jc*32+jr)*256 + c0 + cc, f32);
      *(uint4*)&WO[jr*128+cc+8] = ld8(wo, (size_t)(jc*32+jr)*256 + c0 + cc + 8, f32);
    }
    __syncthreads();
    #pragma unroll 4
    for (int jj=0;jj<32;++jj) {
      float wv = bf2f(WC[ty*256 + jc*32 + jj]);
      short8 w8 = *(const short8*)&WO[jj*128 + tx*8];
      #pragma unroll
      for (int i=0;i<8;++i) acc[i] += wv * bf2f((u16)w8[i]);
    }
  }
  {
    u32 pw[4];
    #pragma unroll
    for (int j=0;j<4;++j) pw[j] = (u32)f2bf(acc[2*j]) | ((u32)f2bf(acc[2*j+1])<<16);
    *(uint4*)&F[(size_t)(o0+ty)*256 + c0 + tx*8] = *(uint4*)pw;
  }
  // parallel bias: b_fused[o] = sum_j wconv[o][j]*bo[j] + bconv[o]   (WC still resident)
  if (blockIdx.y == 0) {
    float s = 0.0f;
    #pragma unroll 4
    for (int j=tx*16; j<tx*16+16; ++j) s += bf2f(WC[ty*256+j]) * ldsc(bo, j, f32);
    bred[ty][tx] = s;
  }
  __syncthreads();
  if (blockIdx.y == 0 && t < 16) {
    float s = 0.0f;
    #pragma unroll
    for (int p=0;p<16;++p) s += bred[t][p];
    bfus[o0+t] = s + ldsc(bconv, o0+t, f32);
  }
}

// ---------------- K0: transpose x (B,C,HW) -> xt (B*HW, C), bf16 (fallback path) ----
__global__ __launch_bounds__(256) void k_transpose(const void* __restrict__ x, u16* __restrict__ xt,
                                                   const int* __restrict__ flagp)
{
  __shared__ int sflag;
  __shared__ __align__(16) u16 tile[64][68];
  if (threadIdx.x == 0) sflag = *flagp;
  __syncthreads();
  const int f32 = sflag;
  const int p0 = blockIdx.x*64, c0 = blockIdx.y*64, b = blockIdx.z;
  const int t = threadIdx.x;
  const size_t xbo = ((size_t)(b*256 + c0))*4096 + p0;
  #pragma unroll
  for (int pass=0; pass<4; ++pass) {
    int cl = pass*16 + (t>>4);
    int pl = (t&15)*4;
    uint2 v = ld4(x, xbo + (size_t)cl*4096 + pl, f32);
    *(uint2*)&tile[cl][pl] = v;
  }
  __syncthreads();
  u16* xtb = xt + ((size_t)b*4096 + p0)*256 + c0;
  #pragma unroll
  for (int pass=0; pass<4; ++pass) {
    int pl = pass*16 + (t>>4);
    int cl = (t&15)*4;
    unsigned int lo = (unsigned int)tile[cl][pl]   | ((unsigned int)tile[cl+1][pl]<<16);
    unsigned int hi = (unsigned int)tile[cl+2][pl] | ((unsigned int)tile[cl+3][pl]<<16);
    uint2 o; o.x = lo; o.y = hi;
    *(uint2*)(xtb + (size_t)pl*256 + cl) = o;
  }
}

// ------------- generic GEMM: C[M,N] = A[M,K] @ Bt[N,K]^T * colscale + bias --------------
// xpose=0: NO-LDS main loop, fragments direct from global (r7-proven).
// xpose=1: A is channel-major x (B,C,HW); A-tile staged to LDS [128px][40] with an
//          inline transpose (16 contiguous px per thread -> 16 ds_write_b16;
//          write banks disjoint per half-wave; frag reads use the proven 80B stride).
//          B must be an internal bf16 arena (internalB=1).
// B split-routed (128-aligned nsplit; scale col<nsplit ? s_lo : s_hi).
// shuffle=1: PixelShuffle(2) epilogue, 4 chunks of 32 cols (r2-proven stores).
__global__ __launch_bounds__(256) void k_gemm_bt(
  const void* __restrict__ A, int lda,
  const void* __restrict__ Bt0, const void* __restrict__ Bt1, int nsplit,
  const void* __restrict__ bias,
  void* __restrict__ C, int M, int N, int K,
  float s_lo, float s_hi, int shuffle, int internalB, int xpose,
  const int* __restrict__ flagp)
{
  __shared__ int sflag;
  __shared__ __align__(16) char smem[18432];
  if (threadIdx.x == 0) sflag = *flagp;
  __syncthreads();
  const int f32 = sflag;
  const int bf = internalB ? 0 : f32;          // dtype of Bt loads
  const int biasf = internalB ? 1 : f32;       // dtype of bias loads
  const int m0 = blockIdx.x*128, n0 = blockIdx.y*128;
  const void* Bs; int boff;
  if (Bt1 && n0 >= nsplit) { Bs = Bt1; boff = n0 - nsplit; } else { Bs = Bt0; boff = n0; }
  const int t = threadIdx.x, lane = t & 63, wv = t >> 6;
  const int wm = (wv & 1)*64, wn = (wv >> 1)*64;
  const int lm = lane & 15, lq = lane >> 4;
  f32x4 acc[4][4] = {};

  if (xpose) {
    // ---- A = x (channel-major), staged+transposed to LDS per K-step ----
    u16* Als = (u16*)smem;                    // 128 x 40 u16
    const int bb = m0 >> 12, px0 = m0 & 4095;
    const int ch = t & 31, pg = t >> 5;       // 32 ch x 8 px-groups
    const u16* Bq = (const u16*)Bs;
    for (int k0 = 0; k0 < K; k0 += 32) {
      if (k0) __syncthreads();                // prev frag reads done
      {
        size_t xo = ((size_t)(bb*256 + k0 + ch))*4096 + px0 + pg*16;
        u16 v[16];
        if (f32) {
          const float* fp = (const float*)A + xo;
          float4 q0 = *(const float4*)fp,     q1 = *(const float4*)(fp+4);
          float4 q2 = *(const float4*)(fp+8), q3 = *(const float4*)(fp+12);
          v[0]=f2bf(q0.x); v[1]=f2bf(q0.y); v[2]=f2bf(q0.z); v[3]=f2bf(q0.w);
          v[4]=f2bf(q1.x); v[5]=f2bf(q1.y); v[6]=f2bf(q1.z); v[7]=f2bf(q1.w);
          v[8]=f2bf(q2.x); v[9]=f2bf(q2.y); v[10]=f2bf(q2.z); v[11]=f2bf(q2.w);
          v[12]=f2bf(q3.x); v[13]=f2bf(q3.y); v[14]=f2bf(q3.z); v[15]=f2bf(q3.w);
        } else {
          const u16* hp = (const u16*)A + xo;
          *(uint4*)&v[0] = *(const uint4*)hp;
          *(uint4*)&v[8] = *(const uint4*)(hp+8);
        }
        #pragma unroll
        for (int j=0;j<16;++j) Als[(pg*16 + j)*40 + ch] = v[j];
      }
      __syncthreads();
      short8 af[4], bfr[4];
      #pragma unroll
      for (int i=0;i<4;++i) af[i] = *(const short8*)&Als[(wm + i*16 + lm)*40 + lq*8];
      #pragma unroll
      for (int i=0;i<4;++i) bfr[i] = *(const short8*)(Bq + (size_t)(boff + wn + i*16 + lm)*K + k0 + lq*8);
      #pragma unroll
      for (int mt=0;mt<4;++mt)
        #pragma unroll
        for (int nt=0;nt<4;++nt)
          acc[mt][nt] = MFMA16(af[mt], bfr[nt], acc[mt][nt]);
    }
  } else {
    // ---- NO-LDS main loop (r7-proven): fragments direct from global ----
    const u16* Au = (const u16*)A;
    const u16* arow[4];
    size_t brow[4];
    #pragma unroll
    for (int i=0;i<4;++i) {
      arow[i] = Au + (size_t)(m0 + wm + i*16 + lm)*lda + lq*8;
      brow[i] = (size_t)(boff + wn + i*16 + lm)*K + lq*8;
    }
    #pragma unroll 2
    for (int k0 = 0; k0 < K; k0 += 32) {
      short8 af[4], bfr[4];
      #pragma unroll
      for (int i=0;i<4;++i) af[i] = *(const short8*)(arow[i] + k0);
      #pragma unroll
      for (int i=0;i<4;++i) { uint4 v = ld8(Bs, brow[i] + k0, bf); bfr[i] = *(const short8*)&v; }
      #pragma unroll
      for (int mt=0;mt<4;++mt)
        #pragma unroll
        for (int nt=0;nt<4;++nt)
          acc[mt][nt] = MFMA16(af[mt], bfr[nt], acc[mt][nt]);
    }
  }

  if (!shuffle) {
    u16* eh = (u16*)smem;   // 128 x 72 u16 (18432B)
    #pragma unroll
    for (int c=0;c<2;++c) {
      __syncthreads();
      if ((wv>>1) == c) {
        #pragma unroll
        for (int nt=0;nt<4;++nt) {
          int col = n0 + c*64 + nt*16 + lm;
          float sc = (col < nsplit) ? s_lo : s_hi;
          float bv = bias ? ldsc(bias, col, biasf) : 0.0f;
          #pragma unroll
          for (int mt=0;mt<4;++mt)
            #pragma unroll
            for (int r=0;r<4;++r) {
              int row = wm + mt*16 + lq*4 + r;
              eh[row*72 + nt*16 + lm] = f2bf(acc[mt][nt][r]*sc + bv);
            }
        }
      }
      __syncthreads();
      {
        int row = t >> 1, off = (t & 1)*32;
        const uint4* s = (const uint4*)&eh[row*72 + off];
        uint4 v0 = s[0], v1 = s[1], v2 = s[2], v3 = s[3];
        uint4* dp = (uint4*)((u16*)C + (size_t)(m0+row)*N + n0 + c*64 + off);
        dp[0]=v0; dp[1]=v1; dp[2]=v2; dp[3]=v3;
      }
    }
  } else {
    // 4 chunks of 32 cols; ef = 32 output-rows x 134 fp32 (17152B)
    float* ef = (float*)smem;
    const int b = m0 >> 12;
    const int hh0 = (m0 & 4095) >> 6;   // tile = 2 image rows (hh0, hh0+1) x 64 px
    #pragma unroll
    for (int c=0;c<4;++c) {
      __syncthreads();
      if ((wv>>1) == (c>>1)) {
        #pragma unroll
        for (int nt2=0;nt2<2;++nt2) {
          int nt = (c&1)*2 + nt2;
          int col = n0 + wn + nt*16 + lm;             // global col
          float bv = bias ? ldsc(bias, col, biasf) : 0.0f;
          int col_rel = nt2*16 + lm;                  // 0..31 within chunk
          int cn_rel = col_rel >> 2, rr = (col_rel >> 1) & 1, ss = col_rel & 1;
          #pragma unroll
          for (int mt=0;mt<4;++mt)
            #pragma unroll
            for (int r=0;r<4;++r) {
              int row = wm + mt*16 + lq*4 + r;        // 0..127 (pixel within tile)
              int orow = cn_rel*4 + (row>>6)*2 + rr;  // output-row within chunk (0..31)
              int ow   = (row & 63)*2 + ss;           // 0..127
              ef[orow*134 + ow] = acc[mt][nt][r]*s_hi + bv;
            }
        }
      }
      __syncthreads();
      {
        int orow = t >> 3, seg = t & 7;               // 8 lanes cover one full 512B row
        int cn_rel = orow >> 2, oh_rel = orow & 3;
        int cn = ((n0 + c*32) >> 2) + cn_rel;
        size_t obase = (((size_t)(b*256 + cn))*128 + hh0*2 + oh_rel)*128 + seg*16;
        const float4* s = (const float4*)&ef[orow*134 + seg*16];
        float4 v0 = s[0], v1 = s[1], v2 = s[2], v3 = s[3];
        if (f32) {
          float4* dp = (float4*)((float*)C + obase);
          dp[0]=v0; dp[1]=v1; dp[2]=v2; dp[3]=v3;
        } else {
          float vv[16];
          *(float4*)&vv[0]=v0; *(float4*)&vv[4]=v1; *(float4*)&vv[8]=v2; *(float4*)&vv[12]=v3;
          u32 pw[8];
          #pragma unroll
          for (int j=0;j<8;++j) pw[j] = (u32)f2bf(vv[2*j]) | ((u32)f2bf(vv[2*j+1])<<16);
          u16* dp = (u16*)C + obase;
          *(uint4*)dp       = *(uint4*)&pw[0];
          *(uint4*)(dp + 8) = *(uint4*)&pw[4];
        }
      }
    }
  }
}

// ---------------- K2: halo attention, one WG per (block, head) ----------------
// Reads fused qkv buffer (stride 768: q | k | v); writes output to
// aout[p*ostride + head*64 + d] (ostride=256 for separate arena, 768 for in-place).
#define MASKVAL (-30000.0f)
__global__ __launch_bounds__(256) void k_halo_attn(
  const u16* __restrict__ qkv,
  const void* __restrict__ relh, const void* __restrict__ relw,
  u16* __restrict__ aout, int ostride,
  const int* __restrict__ flagp)
{
  __shared__ int sflag;
  __shared__ __align__(16) u16 Qs[64*72];
  __shared__ __align__(16) u16 KP[128*72];
  __shared__ __align__(16) u16 Vt[64*136];
  __shared__ __align__(16) u16 Gw[64*32];
  __shared__ __align__(16) u16 Gh[64*32];
  if (threadIdx.x == 0) sflag = *flagp;
  __syncthreads();
  const int f32 = sflag;

  const int blk = blockIdx.x, head = blockIdx.y;
  const int bb = blk >> 6, by = (blk >> 3) & 7, bx = blk & 7;
  const int h0 = by*8, w0 = bx*8;
  const int t = threadIdx.x, lane = t & 63, wv = t >> 6;
  const int lm = lane & 15, lq = lane >> 4;
  const size_t pixbase = (size_t)bb * 4096;
  const float LOG2E = 1.4426950408889634f;

  #pragma unroll
  for (int i=0;i<2;++i) {
    int u = t + i*256;
    int row = u >> 3, ch = (u & 7)*8;
    int qx = row >> 3, qy = row & 7;
    size_t p = pixbase + (size_t)(h0+qx)*64 + (w0+qy);
    *(uint4*)&Qs[row*72 + ch] = *(const uint4*)(qkv + p*768 + head*64 + ch);
  }
  {
    u16* RW = KP; u16* RH = KP + 2048;
    if (t < 248) {
      *(uint4*)&RW[t*8] = ld8(relw, (size_t)t*8, f32);
      *(uint4*)&RH[t*8] = ld8(relh, (size_t)t*8, f32);
    } else {
      uint4 z; z.x=z.y=z.z=z.w=0;
      int o = 1984 + (t-248)*8;
      *(uint4*)&RW[o] = z;
      *(uint4*)&RH[o] = z;
    }
  }
  __syncthreads();
  {
    const u16* RW = KP; const u16* RH = KP + 2048;
    f32x4 agw[2] = {}, agh[2] = {};
    #pragma unroll
    for (int ks=0;ks<2;++ks) {
      short8 aq = *(const short8*)&Qs[(wv*16 + lm)*72 + ks*32 + lq*8];
      #pragma unroll
      for (int nt=0;nt<2;++nt) {
        short8 bw = *(const short8*)&RW[(nt*16 + lm)*64 + ks*32 + lq*8];
        short8 bh = *(const short8*)&RH[(nt*16 + lm)*64 + ks*32 + lq*8];
        agw[nt] = MFMA16(aq, bw, agw[nt]);
        agh[nt] = MFMA16(aq, bh, agh[nt]);
      }
    }
    #pragma unroll
    for (int nt=0;nt<2;++nt)
      #pragma unroll
      for (int r=0;r<4;++r) {
        int m = wv*16 + lq*4 + r, c = nt*16 + lm;
        Gw[m*32 + c] = f2bf(agw[nt][r]);
        Gh[m*32 + c] = f2bf(agh[nt][r]);
      }
  }
  __syncthreads();

  float m_run[4], l_run[4];
  #pragma unroll
  for (int r=0;r<4;++r){ m_run[r] = MASKVAL; l_run[r] = 0.0f; }
  f32x4 acc_o[4] = {};

  for (int tile=0; tile<2; ++tile) {
    #pragma unroll
    for (int i=0;i<4;++i) {
      int u = t + i*256;
      int kl = u >> 3, ch = (u & 7)*8;
      int ki = tile*8 + (kl >> 4), kj = kl & 15;
      int hk = h0 - 4 + ki, wk = w0 - 4 + kj;
      uint4 v; v.x=v.y=v.z=v.w=0;
      if ((unsigned)hk < 64u && (unsigned)wk < 64u) {
        size_t p = pixbase + (size_t)hk*64 + wk;
        v = *(const uint4*)(qkv + p*768 + 256 + head*64 + ch);
      }
      *(uint4*)&KP[kl*72 + ch] = v;
    }
    {
      int kl = t & 127, db = (t >> 7)*32;
      int ki = tile*8 + (kl >> 4), kj = kl & 15;
      int hk = h0 - 4 + ki, wk = w0 - 4 + kj;
      bool ok = ((unsigned)hk < 64u) && ((unsigned)wk < 64u);
      size_t p = pixbase + (size_t)hk*64 + wk;
      const u16* vp = qkv + p*768 + 512 + head*64 + db;
      #pragma unroll
      for (int c=0;c<4;++c) {
        union { uint4 v; u16 s[8]; } uu;
        uu.v.x=uu.v.y=uu.v.z=uu.v.w=0;
        if (ok) uu.v = *(const uint4*)(vp + c*8);
        #pragma unroll
        for (int jj=0;jj<8;++jj) Vt[(db + c*8 + jj)*136 + kl] = uu.s[jj];
      }
    }
    __syncthreads();
    f32x4 as[8] = {};
    #pragma unroll
    for (int ks=0;ks<2;++ks) {
      short8 aq = *(const short8*)&Qs[(wv*16 + lm)*72 + ks*32 + lq*8];
      #pragma unroll
      for (int nt=0;nt<8;++nt) {
        short8 bk = *(const short8*)&KP[(nt*16 + lm)*72 + ks*32 + lq*8];
        as[nt] = MFMA16(aq, bk, as[nt]);
      }
    }
    __syncthreads();
    #pragma unroll
    for (int r=0;r<4;++r) {
      int m = wv*16 + lq*4 + r;
      int qx = m >> 3, qy = m & 7;
      float vals[8]; float rowmax = MASKVAL;
      #pragma unroll
      for (int nt=0;nt<8;++nt) {
        int ki = tile*8 + nt;
        int hk = h0 - 4 + ki, wk = w0 - 4 + lm;
        float v = as[nt][r]
                + bf2f(Gw[m*32 + (lm - qy + 15)])
                + bf2f(Gh[m*32 + (ki - qx + 15)]);
        if (!((unsigned)hk < 64u && (unsigned)wk < 64u)) v = MASKVAL;
        vals[nt] = v;
        rowmax = fmaxf(rowmax, v);
      }
      #pragma unroll
      for (int s=1;s<16;s<<=1) rowmax = fmaxf(rowmax, __shfl_xor(rowmax, s, 64));
      float mnew = fmaxf(m_run[r], rowmax);
      float alpha = exp2f((m_run[r] - mnew)*LOG2E);
      float rs = 0.0f;
      #pragma unroll
      for (int nt=0;nt<8;++nt) {
        float e = exp2f((vals[nt] - mnew)*LOG2E);
        rs += e;
        KP[m*136 + nt*16 + lm] = f2bf(e);
      }
      #pragma unroll
      for (int s=1;s<16;s<<=1) rs += __shfl_xor(rs, s, 64);
      l_run[r] = l_run[r]*alpha + rs;
      m_run[r] = mnew;
      #pragma unroll
      for (int nt=0;nt<4;++nt) acc_o[nt][r] *= alpha;
    }
    __syncthreads();
    #pragma unroll
    for (int ks=0;ks<4;++ks) {
      short8 ap = *(const short8*)&KP[(wv*16 + lm)*136 + ks*32 + lq*8];
      #pragma unroll
      for (int nt=0;nt<4;++nt) {
        short8 bv = *(const short8*)&Vt[(nt*16 + lm)*136 + ks*32 + lq*8];
        acc_o[nt] = MFMA16(ap, bv, acc_o[nt]);
      }
    }
    __syncthreads();
  }
  #pragma unroll
  for (int nt=0;nt<4;++nt)
    #pragma unroll
    for (int r=0;r<4;++r) {
      int m = wv*16 + lq*4 + r;
      int qx = m >> 3, qy = m & 7;
      size_t p = pixbase + (size_t)(h0+qx)*64 + (w0+qy);
      aout[p*(size_t)ostride + head*64 + nt*16 + lm] = f2bf(acc_o[nt][r]/l_run[r]);
    }
}

extern "C" void kernel_launch(void* const* d_in, const int* in_sizes, int n_in,
                              void* d_out, int out_size, void* d_ws, size_t ws_size,
                              hipStream_t stream)
{
  const void* x     = d_in[0];
  const void* wq    = d_in[1];
  const void* wkv   = d_in[2];
  const void* wo    = d_in[3];
  const void* bo    = d_in[4];
  const void* relh  = d_in[5];
  const void* relw  = d_in[6];
  const void* wconv = d_in[7];
  const void* bconv = d_in[8];

  int*  flag = (int*)d_ws;
  u16*  base = (u16*)d_out;
  u16*  qkv  = base;                            // 32768 x 768 bf16 (q | k | v)
  u16*  xt   = base + 25165824;                 // 32768 x 256 bf16 (fallback only)

  const size_t WS_FUSED = 4096 + 524288 + 4096 + 16777216;  // flag|Wf|bf|aout

  if (ws_size >= WS_FUSED) {
    // ---- fused path: wo folded into conv; weights pre-converted; transpose inline ----
    u16*   Wf   = (u16*)((char*)d_ws + 4096);
    float* bfus = (float*)((char*)d_ws + 4096 + 524288);
    u16*   aout = (u16*)((char*)d_ws + 4096 + 524288 + 4096);
    u16*   Wqkv = aout;    // 768x256 bf16 (393KB) in aout region; dead before attn writes
    k_fuse_w<<<dim3(64,3), 256, 0, stream>>>((const u32*)x, wq, wkv, wo, wconv, bo, bconv,
                                             Wf, bfus, Wqkv, flag);
    // qkv projection straight from x (inline transpose), bf16 weights
    k_gemm_bt<<<dim3(256,6), 256, 0, stream>>>(x, 0, Wqkv, nullptr, 256, nullptr,
                                               qkv, 32768, 768, 256, 0.125f, 1.0f, 0, 1, 1, flag);
    k_halo_attn<<<dim3(512,4), 256, 0, stream>>>(qkv, relh, relw, aout, 256, flag);
    k_gemm_bt<<<dim3(256,8), 256, 0, stream>>>(aout, 256, Wf, nullptr, 0, bfus,
                                               d_out, 32768, 1024, 256, 1.0f, 1.0f, 1, 1, 0, flag);
  } else {
    // ---- fallback (r2 pipeline): separate transpose + wo-GEMM through y2 in ws ----
    u16* y2 = (u16*)((char*)d_ws + 4096);
    k_detect<<<1, 256, 0, stream>>>((const u32*)x, flag);
    k_transpose<<<dim3(64,4,8), 256, 0, stream>>>(x, xt, flag);
    k_gemm_bt<<<dim3(256,6), 256, 0, stream>>>(xt, 256, wq, wkv, 256, nullptr,
                                               qkv, 32768, 768, 256, 0.125f, 1.0f, 0, 0, 0, flag);
    k_halo_attn<<<dim3(512,4), 256, 0, stream>>>(qkv, relh, relw, qkv, 768, flag);
    k_gemm_bt<<<dim3(256,2), 256, 0, stream>>>(qkv, 768, wo, nullptr, 0, bo,
                                               y2, 32768, 256, 256, 1.0f, 1.0f, 0, 0, 0, flag);
    k_gemm_bt<<<dim3(256,8), 256, 0, stream>>>(y2, 256, wconv, nullptr, 0, bconv,
                                               d_out, 32768, 1024, 256, 1.0f, 1.0f, 1, 0, 0, flag);
  }
}

// Round 9
// 365.976 us; speedup vs baseline: 1.1135x; 1.0049x over previous
//
#include <hip/hip_runtime.h>

typedef unsigned short u16;
typedef unsigned int u32;
typedef __attribute__((ext_vector_type(8))) short short8;
typedef __attribute__((ext_vector_type(4))) float f32x4;

__device__ __forceinline__ float bf2f(u16 u){ union { u32 i; float f; } x; x.i = ((u32)u)<<16; return x.f; }
__device__ __forceinline__ u16 f2bf(float f){ union { float f; u32 i; } x; x.f = f; u32 r = x.i + 0x7fffu + ((x.i>>16)&1u); return (u16)(r>>16); }

#define MFMA16(a,b,c) __builtin_amdgcn_mfma_f32_16x16x32_bf16((a),(b),(c),0,0,0)

// ---- dual-dtype external loads: fp32 inputs are converted to bf16 at ingest ----
__device__ __forceinline__ uint4 ld8(const void* p, size_t off, int f32) {
  if (f32) {
    const float* fp = (const float*)p + off;
    float4 a = *(const float4*)fp;
    float4 b = *(const float4*)(fp + 4);
    uint4 o;
    o.x = (u32)f2bf(a.x) | ((u32)f2bf(a.y)<<16);
    o.y = (u32)f2bf(a.z) | ((u32)f2bf(a.w)<<16);
    o.z = (u32)f2bf(b.x) | ((u32)f2bf(b.y)<<16);
    o.w = (u32)f2bf(b.z) | ((u32)f2bf(b.w)<<16);
    return o;
  }
  return *(const uint4*)((const u16*)p + off);
}
__device__ __forceinline__ uint2 ld4(const void* p, size_t off, int f32) {
  if (f32) {
    const float* fp = (const float*)p + off;
    float4 a = *(const float4*)fp;
    uint2 o;
    o.x = (u32)f2bf(a.x) | ((u32)f2bf(a.y)<<16);
    o.y = (u32)f2bf(a.z) | ((u32)f2bf(a.w)<<16);
    return o;
  }
  return *(const uint2*)((const u16*)p + off);
}
__device__ __forceinline__ float ldsc(const void* p, size_t off, int f32) {
  if (f32) return ((const float*)p)[off];
  return bf2f(((const u16*)p)[off]);
}

// ---- K-1: detect input dtype from x's low 16 bits (bf16 exponent vs fp32 mantissa) ----
__global__ __launch_bounds__(256) void k_detect(const u32* __restrict__ x, int* __restrict__ flag)
{
  __shared__ int cnt;
  if (threadIdx.x == 0) cnt = 0;
  __syncthreads();
  int c = 0;
  #pragma unroll
  for (int i = 0; i < 32; ++i) {
    u32 w = x[threadIdx.x*32 + i];
    u32 e = (w >> 7) & 0xFFu;
    c += (e == 0u || (e >= 96u && e <= 143u)) ? 1 : 0;
  }
  atomicAdd(&cnt, c);
  __syncthreads();
  if (threadIdx.x == 0) *flag = (cnt < 4915) ? 1 : 0;
}

// ---- K-fuse: y=0,1: W_fused = wconv @ wo (bf16) + b_fused; y=2: convert wq|wkv
// to bf16 arena Wqkv[768][256]. All WGs do a local dtype vote; WG(0,0) publishes.
__global__ __launch_bounds__(256) void k_fuse_w(
  const u32* __restrict__ x,
  const void* __restrict__ wq, const void* __restrict__ wkv,
  const void* __restrict__ wo, const void* __restrict__ wconv,
  const void* __restrict__ bo, const void* __restrict__ bconv,
  u16* __restrict__ F, float* __restrict__ bfus, u16* __restrict__ Wqkv,
  int* __restrict__ flagp)
{
  __shared__ int cnt;
  __shared__ __align__(16) u16 WC[16*256];   // wconv o-block, bf16
  __shared__ __align__(16) u16 WO[32*128];   // wo j-chunk x c-half, bf16
  __shared__ float bred[16][17];
  const int t = threadIdx.x;
  if (t == 0) cnt = 0;
  __syncthreads();
  {
    int c = 0;
    #pragma unroll
    for (int i=0;i<8;++i) {
      u32 w = x[t*8+i];
      u32 e = (w>>7)&0xFFu;
      c += (e==0u || (e>=96u && e<=143u)) ? 1 : 0;
    }
    atomicAdd(&cnt, c);
  }
  __syncthreads();
  const int f32 = (cnt < 1229) ? 1 : 0;     // 2048 words: bf16 ~2048, fp32 ~390
  if (blockIdx.x == 0 && blockIdx.y == 0 && t == 0) *flagp = f32;

  if (blockIdx.y == 2) {
    // convert wq (rows 0..255) | wkv (rows 256..767) -> Wqkv bf16
    int rbase = blockIdx.x * 12;            // 64 WGs x 12 rows = 768
    #pragma unroll
    for (int p=0;p<2;++p) {
      int rr = p*8 + (t>>5);                // 0..15
      int cg = (t&31)*8;                    // 0..248
      if (rr < 12) {
        int row = rbase + rr;
        uint4 w = (row < 256) ? ld8(wq, (size_t)row*256 + cg, f32)
                              : ld8(wkv, (size_t)(row-256)*256 + cg, f32);
        *(uint4*)&Wqkv[(size_t)row*256 + cg] = w;
      }
    }
    return;
  }

  const int o0 = blockIdx.x*16, c0 = blockIdx.y*128;
  {
    int row = t>>4, ch = (t&15)*16;
    *(uint4*)&WC[row*256+ch]     = ld8(wconv, (size_t)(o0+row)*256 + ch, f32);
    *(uint4*)&WC[row*256+ch+8]   = ld8(wconv, (size_t)(o0+row)*256 + ch + 8, f32);
  }
  float acc[8] = {};
  const int ty = t>>4, tx = t&15;
  for (int jc=0;jc<8;++jc) {
    __syncthreads();    // (jc=0: also covers WC staging) protect WO reuse
    {
      int jr = t>>3, cc = (t&7)*16;
      *(uint4*)&WO[jr*128+cc]   = ld8(wo, (size_t)(jc*32+jr)*256 + c0 + cc, f32);
      *(uint4*)&WO[jr*128+cc+8] = ld8(wo, (size_t)(jc*32+jr)*256 + c0 + cc + 8, f32);
    }
    __syncthreads();
    #pragma unroll 4
    for (int jj=0;jj<32;++jj) {
      float wv = bf2f(WC[ty*256 + jc*32 + jj]);
      short8 w8 = *(const short8*)&WO[jj*128 + tx*8];
      #pragma unroll
      for (int i=0;i<8;++i) acc[i] += wv * bf2f((u16)w8[i]);
    }
  }
  {
    u32 pw[4];
    #pragma unroll
    for (int j=0;j<4;++j) pw[j] = (u32)f2bf(acc[2*j]) | ((u32)f2bf(acc[2*j+1])<<16);
    *(uint4*)&F[(size_t)(o0+ty)*256 + c0 + tx*8] = *(uint4*)pw;
  }
  // parallel bias: b_fused[o] = sum_j wconv[o][j]*bo[j] + bconv[o]   (WC still resident)
  if (blockIdx.y == 0) {
    float s = 0.0f;
    #pragma unroll 4
    for (int j=tx*16; j<tx*16+16; ++j) s += bf2f(WC[ty*256+j]) * ldsc(bo, j, f32);
    bred[ty][tx] = s;
  }
  __syncthreads();
  if (blockIdx.y == 0 && t < 16) {
    float s = 0.0f;
    #pragma unroll
    for (int p=0;p<16;++p) s += bred[t][p];
    bfus[o0+t] = s + ldsc(bconv, o0+t, f32);
  }
}

// ---------------- K0: transpose x (B,C,HW) -> xt (B*HW, C), bf16 (fallback path) ----
__global__ __launch_bounds__(256) void k_transpose(const void* __restrict__ x, u16* __restrict__ xt,
                                                   const int* __restrict__ flagp)
{
  __shared__ int sflag;
  __shared__ __align__(16) u16 tile[64][68];
  if (threadIdx.x == 0) sflag = *flagp;
  __syncthreads();
  const int f32 = sflag;
  const int p0 = blockIdx.x*64, c0 = blockIdx.y*64, b = blockIdx.z;
  const int t = threadIdx.x;
  const size_t xbo = ((size_t)(b*256 + c0))*4096 + p0;
  #pragma unroll
  for (int pass=0; pass<4; ++pass) {
    int cl = pass*16 + (t>>4);
    int pl = (t&15)*4;
    uint2 v = ld4(x, xbo + (size_t)cl*4096 + pl, f32);
    *(uint2*)&tile[cl][pl] = v;
  }
  __syncthreads();
  u16* xtb = xt + ((size_t)b*4096 + p0)*256 + c0;
  #pragma unroll
  for (int pass=0; pass<4; ++pass) {
    int pl = pass*16 + (t>>4);
    int cl = (t&15)*4;
    unsigned int lo = (unsigned int)tile[cl][pl]   | ((unsigned int)tile[cl+1][pl]<<16);
    unsigned int hi = (unsigned int)tile[cl+2][pl] | ((unsigned int)tile[cl+3][pl]<<16);
    uint2 o; o.x = lo; o.y = hi;
    *(uint2*)(xtb + (size_t)pl*256 + cl) = o;
  }
}

// ------------- generic GEMM: C[M,N] = A[M,K] @ Bt[N,K]^T * colscale + bias --------------
// xpose=0: NO-LDS main loop, fragments direct from global (r7-proven).
// xpose=1: A is channel-major x (B,C,HW); A-tile staged to LDS [128px][40] with an
//          inline transpose. B must be an internal bf16 arena (internalB=1).
// swz=1: XCD-aware bijective remap — the gridDim.y col-blocks of one m-tile become
//        dispatch-adjacent on the SAME XCD (id%8 preserved), so the shared A-tile
//        hits that XCD's L2 instead of L3. Requires gridDim.x % 8 == 0.
// B split-routed (128-aligned nsplit; scale col<nsplit ? s_lo : s_hi).
// shuffle=1: PixelShuffle(2) epilogue, 4 chunks of 32 cols (r2-proven stores).
__global__ __launch_bounds__(256) void k_gemm_bt(
  const void* __restrict__ A, int lda,
  const void* __restrict__ Bt0, const void* __restrict__ Bt1, int nsplit,
  const void* __restrict__ bias,
  void* __restrict__ C, int M, int N, int K,
  float s_lo, float s_hi, int shuffle, int internalB, int xpose, int swz,
  const int* __restrict__ flagp)
{
  __shared__ int sflag;
  __shared__ __align__(16) char smem[18432];
  if (threadIdx.x == 0) sflag = *flagp;
  __syncthreads();
  const int f32 = sflag;
  const int bf = internalB ? 0 : f32;          // dtype of Bt loads
  const int biasf = internalB ? 1 : f32;       // dtype of bias loads
  int bx = blockIdx.x, by = blockIdx.y;
  if (swz) {
    int id  = by * gridDim.x + bx;
    int xcd = id & 7, idx = id >> 3;
    int ny  = gridDim.y, per = gridDim.x >> 3;
    bx = xcd * per + idx / ny;
    by = idx % ny;
  }
  const int m0 = bx*128, n0 = by*128;
  const void* Bs; int boff;
  if (Bt1 && n0 >= nsplit) { Bs = Bt1; boff = n0 - nsplit; } else { Bs = Bt0; boff = n0; }
  const int t = threadIdx.x, lane = t & 63, wv = t >> 6;
  const int wm = (wv & 1)*64, wn = (wv >> 1)*64;
  const int lm = lane & 15, lq = lane >> 4;
  f32x4 acc[4][4] = {};

  if (xpose) {
    // ---- A = x (channel-major), staged+transposed to LDS per K-step ----
    u16* Als = (u16*)smem;                    // 128 x 40 u16
    const int bb = m0 >> 12, px0 = m0 & 4095;
    const int ch = t & 31, pg = t >> 5;       // 32 ch x 8 px-groups
    const u16* Bq = (const u16*)Bs;
    for (int k0 = 0; k0 < K; k0 += 32) {
      if (k0) __syncthreads();                // prev frag reads done
      {
        size_t xo = ((size_t)(bb*256 + k0 + ch))*4096 + px0 + pg*16;
        u16 v[16];
        if (f32) {
          const float* fp = (const float*)A + xo;
          float4 q0 = *(const float4*)fp,     q1 = *(const float4*)(fp+4);
          float4 q2 = *(const float4*)(fp+8), q3 = *(const float4*)(fp+12);
          v[0]=f2bf(q0.x); v[1]=f2bf(q0.y); v[2]=f2bf(q0.z); v[3]=f2bf(q0.w);
          v[4]=f2bf(q1.x); v[5]=f2bf(q1.y); v[6]=f2bf(q1.z); v[7]=f2bf(q1.w);
          v[8]=f2bf(q2.x); v[9]=f2bf(q2.y); v[10]=f2bf(q2.z); v[11]=f2bf(q2.w);
          v[12]=f2bf(q3.x); v[13]=f2bf(q3.y); v[14]=f2bf(q3.z); v[15]=f2bf(q3.w);
        } else {
          const u16* hp = (const u16*)A + xo;
          *(uint4*)&v[0] = *(const uint4*)hp;
          *(uint4*)&v[8] = *(const uint4*)(hp+8);
        }
        #pragma unroll
        for (int j=0;j<16;++j) Als[(pg*16 + j)*40 + ch] = v[j];
      }
      __syncthreads();
      short8 af[4], bfr[4];
      #pragma unroll
      for (int i=0;i<4;++i) af[i] = *(const short8*)&Als[(wm + i*16 + lm)*40 + lq*8];
      #pragma unroll
      for (int i=0;i<4;++i) bfr[i] = *(const short8*)(Bq + (size_t)(boff + wn + i*16 + lm)*K + k0 + lq*8);
      #pragma unroll
      for (int mt=0;mt<4;++mt)
        #pragma unroll
        for (int nt=0;nt<4;++nt)
          acc[mt][nt] = MFMA16(af[mt], bfr[nt], acc[mt][nt]);
    }
  } else {
    // ---- NO-LDS main loop (r7-proven): fragments direct from global ----
    const u16* Au = (const u16*)A;
    const u16* arow[4];
    size_t brow[4];
    #pragma unroll
    for (int i=0;i<4;++i) {
      arow[i] = Au + (size_t)(m0 + wm + i*16 + lm)*lda + lq*8;
      brow[i] = (size_t)(boff + wn + i*16 + lm)*K + lq*8;
    }
    #pragma unroll 2
    for (int k0 = 0; k0 < K; k0 += 32) {
      short8 af[4], bfr[4];
      #pragma unroll
      for (int i=0;i<4;++i) af[i] = *(const short8*)(arow[i] + k0);
      #pragma unroll
      for (int i=0;i<4;++i) { uint4 v = ld8(Bs, brow[i] + k0, bf); bfr[i] = *(const short8*)&v; }
      #pragma unroll
      for (int mt=0;mt<4;++mt)
        #pragma unroll
        for (int nt=0;nt<4;++nt)
          acc[mt][nt] = MFMA16(af[mt], bfr[nt], acc[mt][nt]);
    }
  }

  if (!shuffle) {
    u16* eh = (u16*)smem;   // 128 x 72 u16 (18432B)
    #pragma unroll
    for (int c=0;c<2;++c) {
      __syncthreads();
      if ((wv>>1) == c) {
        #pragma unroll
        for (int nt=0;nt<4;++nt) {
          int col = n0 + c*64 + nt*16 + lm;
          float sc = (col < nsplit) ? s_lo : s_hi;
          float bv = bias ? ldsc(bias, col, biasf) : 0.0f;
          #pragma unroll
          for (int mt=0;mt<4;++mt)
            #pragma unroll
            for (int r=0;r<4;++r) {
              int row = wm + mt*16 + lq*4 + r;
              eh[row*72 + nt*16 + lm] = f2bf(acc[mt][nt][r]*sc + bv);
            }
        }
      }
      __syncthreads();
      {
        int row = t >> 1, off = (t & 1)*32;
        const uint4* s = (const uint4*)&eh[row*72 + off];
        uint4 v0 = s[0], v1 = s[1], v2 = s[2], v3 = s[3];
        uint4* dp = (uint4*)((u16*)C + (size_t)(m0+row)*N + n0 + c*64 + off);
        dp[0]=v0; dp[1]=v1; dp[2]=v2; dp[3]=v3;
      }
    }
  } else {
    // 4 chunks of 32 cols; ef = 32 output-rows x 134 fp32 (17152B)
    float* ef = (float*)smem;
    const int b = m0 >> 12;
    const int hh0 = (m0 & 4095) >> 6;   // tile = 2 image rows (hh0, hh0+1) x 64 px
    #pragma unroll
    for (int c=0;c<4;++c) {
      __syncthreads();
      if ((wv>>1) == (c>>1)) {
        #pragma unroll
        for (int nt2=0;nt2<2;++nt2) {
          int nt = (c&1)*2 + nt2;
          int col = n0 + wn + nt*16 + lm;             // global col
          float bv = bias ? ldsc(bias, col, biasf) : 0.0f;
          int col_rel = nt2*16 + lm;                  // 0..31 within chunk
          int cn_rel = col_rel >> 2, rr = (col_rel >> 1) & 1, ss = col_rel & 1;
          #pragma unroll
          for (int mt=0;mt<4;++mt)
            #pragma unroll
            for (int r=0;r<4;++r) {
              int row = wm + mt*16 + lq*4 + r;        // 0..127 (pixel within tile)
              int orow = cn_rel*4 + (row>>6)*2 + rr;  // output-row within chunk (0..31)
              int ow   = (row & 63)*2 + ss;           // 0..127
              ef[orow*134 + ow] = acc[mt][nt][r]*s_hi + bv;
            }
        }
      }
      __syncthreads();
      {
        int orow = t >> 3, seg = t & 7;               // 8 lanes cover one full 512B row
        int cn_rel = orow >> 2, oh_rel = orow & 3;
        int cn = ((n0 + c*32) >> 2) + cn_rel;
        size_t obase = (((size_t)(b*256 + cn))*128 + hh0*2 + oh_rel)*128 + seg*16;
        const float4* s = (const float4*)&ef[orow*134 + seg*16];
        float4 v0 = s[0], v1 = s[1], v2 = s[2], v3 = s[3];
        if (f32) {
          float4* dp = (float4*)((float*)C + obase);
          dp[0]=v0; dp[1]=v1; dp[2]=v2; dp[3]=v3;
        } else {
          float vv[16];
          *(float4*)&vv[0]=v0; *(float4*)&vv[4]=v1; *(float4*)&vv[8]=v2; *(float4*)&vv[12]=v3;
          u32 pw[8];
          #pragma unroll
          for (int j=0;j<8;++j) pw[j] = (u32)f2bf(vv[2*j]) | ((u32)f2bf(vv[2*j+1])<<16);
          u16* dp = (u16*)C + obase;
          *(uint4*)dp       = *(uint4*)&pw[0];
          *(uint4*)(dp + 8) = *(uint4*)&pw[4];
        }
      }
    }
  }
}

// ---------------- K2: halo attention, one WG per (block, head) ----------------
// Reads fused qkv buffer (stride 768: q | k | v); writes output to
// aout[p*ostride + head*64 + d] (ostride=256 for separate arena, 768 for in-place).
// swz=1: XCD-aware remap — each XCD owns one image (64 blocks x 4 heads); its ~4MB
// KV panel fits that XCD's L2; all 4 heads of a block are dispatch-adjacent.
#define MASKVAL (-30000.0f)
__global__ __launch_bounds__(256) void k_halo_attn(
  const u16* __restrict__ qkv,
  const void* __restrict__ relh, const void* __restrict__ relw,
  u16* __restrict__ aout, int ostride, int swz,
  const int* __restrict__ flagp)
{
  __shared__ int sflag;
  __shared__ __align__(16) u16 Qs[64*72];
  __shared__ __align__(16) u16 KP[128*72];
  __shared__ __align__(16) u16 Vt[64*136];
  __shared__ __align__(16) u16 Gw[64*32];
  __shared__ __align__(16) u16 Gh[64*32];
  if (threadIdx.x == 0) sflag = *flagp;
  __syncthreads();
  const int f32 = sflag;

  int blk = blockIdx.x, head = blockIdx.y;
  if (swz) {
    int id  = blockIdx.y * gridDim.x + blockIdx.x;
    int xcd = id & 7, idx = id >> 3;
    int per = gridDim.x >> 3;                 // blocks per xcd (=64)
    blk  = xcd * per + idx / gridDim.y;
    head = idx % gridDim.y;
  }
  const int bb = blk >> 6, by = (blk >> 3) & 7, bx = blk & 7;
  const int h0 = by*8, w0 = bx*8;
  const int t = threadIdx.x, lane = t & 63, wv = t >> 6;
  const int lm = lane & 15, lq = lane >> 4;
  const size_t pixbase = (size_t)bb * 4096;
  const float LOG2E = 1.4426950408889634f;

  #pragma unroll
  for (int i=0;i<2;++i) {
    int u = t + i*256;
    int row = u >> 3, ch = (u & 7)*8;
    int qx = row >> 3, qy = row & 7;
    size_t p = pixbase + (size_t)(h0+qx)*64 + (w0+qy);
    *(uint4*)&Qs[row*72 + ch] = *(const uint4*)(qkv + p*768 + head*64 + ch);
  }
  {
    u16* RW = KP; u16* RH = KP + 2048;
    if (t < 248) {
      *(uint4*)&RW[t*8] = ld8(relw, (size_t)t*8, f32);
      *(uint4*)&RH[t*8] = ld8(relh, (size_t)t*8, f32);
    } else {
      uint4 z; z.x=z.y=z.z=z.w=0;
      int o = 1984 + (t-248)*8;
      *(uint4*)&RW[o] = z;
      *(uint4*)&RH[o] = z;
    }
  }
  __syncthreads();
  {
    const u16* RW = KP; const u16* RH = KP + 2048;
    f32x4 agw[2] = {}, agh[2] = {};
    #pragma unroll
    for (int ks=0;ks<2;++ks) {
      short8 aq = *(const short8*)&Qs[(wv*16 + lm)*72 + ks*32 + lq*8];
      #pragma unroll
      for (int nt=0;nt<2;++nt) {
        short8 bw = *(const short8*)&RW[(nt*16 + lm)*64 + ks*32 + lq*8];
        short8 bh = *(const short8*)&RH[(nt*16 + lm)*64 + ks*32 + lq*8];
        agw[nt] = MFMA16(aq, bw, agw[nt]);
        agh[nt] = MFMA16(aq, bh, agh[nt]);
      }
    }
    #pragma unroll
    for (int nt=0;nt<2;++nt)
      #pragma unroll
      for (int r=0;r<4;++r) {
        int m = wv*16 + lq*4 + r, c = nt*16 + lm;
        Gw[m*32 + c] = f2bf(agw[nt][r]);
        Gh[m*32 + c] = f2bf(agh[nt][r]);
      }
  }
  __syncthreads();

  float m_run[4], l_run[4];
  #pragma unroll
  for (int r=0;r<4;++r){ m_run[r] = MASKVAL; l_run[r] = 0.0f; }
  f32x4 acc_o[4] = {};

  for (int tile=0; tile<2; ++tile) {
    #pragma unroll
    for (int i=0;i<4;++i) {
      int u = t + i*256;
      int kl = u >> 3, ch = (u & 7)*8;
      int ki = tile*8 + (kl >> 4), kj = kl & 15;
      int hk = h0 - 4 + ki, wk = w0 - 4 + kj;
      uint4 v; v.x=v.y=v.z=v.w=0;
      if ((unsigned)hk < 64u && (unsigned)wk < 64u) {
        size_t p = pixbase + (size_t)hk*64 + wk;
        v = *(const uint4*)(qkv + p*768 + 256 + head*64 + ch);
      }
      *(uint4*)&KP[kl*72 + ch] = v;
    }
    {
      int kl = t & 127, db = (t >> 7)*32;
      int ki = tile*8 + (kl >> 4), kj = kl & 15;
      int hk = h0 - 4 + ki, wk = w0 - 4 + kj;
      bool ok = ((unsigned)hk < 64u) && ((unsigned)wk < 64u);
      size_t p = pixbase + (size_t)hk*64 + wk;
      const u16* vp = qkv + p*768 + 512 + head*64 + db;
      #pragma unroll
      for (int c=0;c<4;++c) {
        union { uint4 v; u16 s[8]; } uu;
        uu.v.x=uu.v.y=uu.v.z=uu.v.w=0;
        if (ok) uu.v = *(const uint4*)(vp + c*8);
        #pragma unroll
        for (int jj=0;jj<8;++jj) Vt[(db + c*8 + jj)*136 + kl] = uu.s[jj];
      }
    }
    __syncthreads();
    f32x4 as[8] = {};
    #pragma unroll
    for (int ks=0;ks<2;++ks) {
      short8 aq = *(const short8*)&Qs[(wv*16 + lm)*72 + ks*32 + lq*8];
      #pragma unroll
      for (int nt=0;nt<8;++nt) {
        short8 bk = *(const short8*)&KP[(nt*16 + lm)*72 + ks*32 + lq*8];
        as[nt] = MFMA16(aq, bk, as[nt]);
      }
    }
    __syncthreads();
    #pragma unroll
    for (int r=0;r<4;++r) {
      int m = wv*16 + lq*4 + r;
      int qx = m >> 3, qy = m & 7;
      float vals[8]; float rowmax = MASKVAL;
      #pragma unroll
      for (int nt=0;nt<8;++nt) {
        int ki = tile*8 + nt;
        int hk = h0 - 4 + ki, wk = w0 - 4 + lm;
        float v = as[nt][r]
                + bf2f(Gw[m*32 + (lm - qy + 15)])
                + bf2f(Gh[m*32 + (ki - qx + 15)]);
        if (!((unsigned)hk < 64u && (unsigned)wk < 64u)) v = MASKVAL;
        vals[nt] = v;
        rowmax = fmaxf(rowmax, v);
      }
      #pragma unroll
      for (int s=1;s<16;s<<=1) rowmax = fmaxf(rowmax, __shfl_xor(rowmax, s, 64));
      float mnew = fmaxf(m_run[r], rowmax);
      float alpha = exp2f((m_run[r] - mnew)*LOG2E);
      float rs = 0.0f;
      #pragma unroll
      for (int nt=0;nt<8;++nt) {
        float e = exp2f((vals[nt] - mnew)*LOG2E);
        rs += e;
        KP[m*136 + nt*16 + lm] = f2bf(e);
      }
      #pragma unroll
      for (int s=1;s<16;s<<=1) rs += __shfl_xor(rs, s, 64);
      l_run[r] = l_run[r]*alpha + rs;
      m_run[r] = mnew;
      #pragma unroll
      for (int nt=0;nt<4;++nt) acc_o[nt][r] *= alpha;
    }
    __syncthreads();
    #pragma unroll
    for (int ks=0;ks<4;++ks) {
      short8 ap = *(const short8*)&KP[(wv*16 + lm)*136 + ks*32 + lq*8];
      #pragma unroll
      for (int nt=0;nt<4;++nt) {
        short8 bv = *(const short8*)&Vt[(nt*16 + lm)*136 + ks*32 + lq*8];
        acc_o[nt] = MFMA16(ap, bv, acc_o[nt]);
      }
    }
    __syncthreads();
  }
  #pragma unroll
  for (int nt=0;nt<4;++nt)
    #pragma unroll
    for (int r=0;r<4;++r) {
      int m = wv*16 + lq*4 + r;
      int qx = m >> 3, qy = m & 7;
      size_t p = pixbase + (size_t)(h0+qx)*64 + (w0+qy);
      aout[p*(size_t)ostride + head*64 + nt*16 + lm] = f2bf(acc_o[nt][r]/l_run[r]);
    }
}

extern "C" void kernel_launch(void* const* d_in, const int* in_sizes, int n_in,
                              void* d_out, int out_size, void* d_ws, size_t ws_size,
                              hipStream_t stream)
{
  const void* x     = d_in[0];
  const void* wq    = d_in[1];
  const void* wkv   = d_in[2];
  const void* wo    = d_in[3];
  const void* bo    = d_in[4];
  const void* relh  = d_in[5];
  const void* relw  = d_in[6];
  const void* wconv = d_in[7];
  const void* bconv = d_in[8];

  int*  flag = (int*)d_ws;
  u16*  base = (u16*)d_out;
  u16*  qkv  = base;                            // 32768 x 768 bf16 (q | k | v)
  u16*  xt   = base + 25165824;                 // 32768 x 256 bf16 (fallback only)

  const size_t WS_FUSED = 4096 + 524288 + 4096 + 16777216;  // flag|Wf|bf|aout

  if (ws_size >= WS_FUSED) {
    // ---- fused path: wo folded into conv; weights pre-converted; transpose inline ----
    u16*   Wf   = (u16*)((char*)d_ws + 4096);
    float* bfus = (float*)((char*)d_ws + 4096 + 524288);
    u16*   aout = (u16*)((char*)d_ws + 4096 + 524288 + 4096);
    u16*   Wqkv = aout;    // 768x256 bf16 (393KB) in aout region; dead before attn writes
    k_fuse_w<<<dim3(64,3), 256, 0, stream>>>((const u32*)x, wq, wkv, wo, wconv, bo, bconv,
                                             Wf, bfus, Wqkv, flag);
    // qkv projection straight from x (inline transpose), bf16 weights, XCD swizzle
    k_gemm_bt<<<dim3(256,6), 256, 0, stream>>>(x, 0, Wqkv, nullptr, 256, nullptr,
                                               qkv, 32768, 768, 256, 0.125f, 1.0f, 0, 1, 1, 1, flag);
    k_halo_attn<<<dim3(512,4), 256, 0, stream>>>(qkv, relh, relw, aout, 256, 1, flag);
    k_gemm_bt<<<dim3(256,8), 256, 0, stream>>>(aout, 256, Wf, nullptr, 0, bfus,
                                               d_out, 32768, 1024, 256, 1.0f, 1.0f, 1, 1, 0, 1, flag);
  } else {
    // ---- fallback (r2 pipeline): separate transpose + wo-GEMM through y2 in ws ----
    u16* y2 = (u16*)((char*)d_ws + 4096);
    k_detect<<<1, 256, 0, stream>>>((const u32*)x, flag);
    k_transpose<<<dim3(64,4,8), 256, 0, stream>>>(x, xt, flag);
    k_gemm_bt<<<dim3(256,6), 256, 0, stream>>>(xt, 256, wq, wkv, 256, nullptr,
                                               qkv, 32768, 768, 256, 0.125f, 1.0f, 0, 0, 0, 0, flag);
    k_halo_attn<<<dim3(512,4), 256, 0, stream>>>(qkv, relh, relw, qkv, 768, 0, flag);
    k_gemm_bt<<<dim3(256,2), 256, 0, stream>>>(qkv, 768, wo, nullptr, 0, bo,
                                               y2, 32768, 256, 256, 1.0f, 1.0f, 0, 0, 0, 0, flag);
    k_gemm_bt<<<dim3(256,8), 256, 0, stream>>>(y2, 256, wconv, nullptr, 0, bconv,
                                               d_out, 32768, 1024, 256, 1.0f, 1.0f, 1, 0, 0, 0, flag);
  }
}

// Round 10
// 365.650 us; speedup vs baseline: 1.1145x; 1.0009x over previous
//
#include <hip/hip_runtime.h>

typedef unsigned short u16;
typedef unsigned int u32;
typedef __attribute__((ext_vector_type(8))) short short8;
typedef __attribute__((ext_vector_type(4))) float f32x4;

__device__ __forceinline__ float bf2f(u16 u){ union { u32 i; float f; } x; x.i = ((u32)u)<<16; return x.f; }
__device__ __forceinline__ u16 f2bf(float f){ union { float f; u32 i; } x; x.f = f; u32 r = x.i + 0x7fffu + ((x.i>>16)&1u); return (u16)(r>>16); }

#define MFMA16(a,b,c) __builtin_amdgcn_mfma_f32_16x16x32_bf16((a),(b),(c),0,0,0)

// Barrier that makes LDS writes/reads visible WITHOUT draining in-flight global
// stores (vmcnt) — epilogue chunks' stores pipeline across it. LDS-reuse safety:
// each thread drains its own lgkm before the barrier, so when all threads have
// passed, all prior ds_reads/ds_writes are complete.
#define LBAR asm volatile("s_waitcnt lgkmcnt(0)\n\ts_barrier" ::: "memory")

// ---- dual-dtype external loads: fp32 inputs are converted to bf16 at ingest ----
__device__ __forceinline__ uint4 ld8(const void* p, size_t off, int f32) {
  if (f32) {
    const float* fp = (const float*)p + off;
    float4 a = *(const float4*)fp;
    float4 b = *(const float4*)(fp + 4);
    uint4 o;
    o.x = (u32)f2bf(a.x) | ((u32)f2bf(a.y)<<16);
    o.y = (u32)f2bf(a.z) | ((u32)f2bf(a.w)<<16);
    o.z = (u32)f2bf(b.x) | ((u32)f2bf(b.y)<<16);
    o.w = (u32)f2bf(b.z) | ((u32)f2bf(b.w)<<16);
    return o;
  }
  return *(const uint4*)((const u16*)p + off);
}
__device__ __forceinline__ uint2 ld4(const void* p, size_t off, int f32) {
  if (f32) {
    const float* fp = (const float*)p + off;
    float4 a = *(const float4*)fp;
    uint2 o;
    o.x = (u32)f2bf(a.x) | ((u32)f2bf(a.y)<<16);
    o.y = (u32)f2bf(a.z) | ((u32)f2bf(a.w)<<16);
    return o;
  }
  return *(const uint2*)((const u16*)p + off);
}
__device__ __forceinline__ float ldsc(const void* p, size_t off, int f32) {
  if (f32) return ((const float*)p)[off];
  return bf2f(((const u16*)p)[off]);
}

// ---- K-1: detect input dtype from x's low 16 bits (bf16 exponent vs fp32 mantissa) ----
__global__ __launch_bounds__(256) void k_detect(const u32* __restrict__ x, int* __restrict__ flag)
{
  __shared__ int cnt;
  if (threadIdx.x == 0) cnt = 0;
  __syncthreads();
  int c = 0;
  #pragma unroll
  for (int i = 0; i < 32; ++i) {
    u32 w = x[threadIdx.x*32 + i];
    u32 e = (w >> 7) & 0xFFu;
    c += (e == 0u || (e >= 96u && e <= 143u)) ? 1 : 0;
  }
  atomicAdd(&cnt, c);
  __syncthreads();
  if (threadIdx.x == 0) *flag = (cnt < 4915) ? 1 : 0;
}

// ---- K-fuse: y=0,1: W_fused = wconv @ wo (bf16) + b_fused; y=2: convert wq|wkv
// to bf16 arena Wqkv[768][256]. All WGs do a local dtype vote; WG(0,0) publishes.
__global__ __launch_bounds__(256) void k_fuse_w(
  const u32* __restrict__ x,
  const void* __restrict__ wq, const void* __restrict__ wkv,
  const void* __restrict__ wo, const void* __restrict__ wconv,
  const void* __restrict__ bo, const void* __restrict__ bconv,
  u16* __restrict__ F, float* __restrict__ bfus, u16* __restrict__ Wqkv,
  int* __restrict__ flagp)
{
  __shared__ int cnt;
  __shared__ __align__(16) u16 WC[16*256];   // wconv o-block, bf16
  __shared__ __align__(16) u16 WO[32*128];   // wo j-chunk x c-half, bf16
  __shared__ float bred[16][17];
  const int t = threadIdx.x;
  if (t == 0) cnt = 0;
  __syncthreads();
  {
    int c = 0;
    #pragma unroll
    for (int i=0;i<8;++i) {
      u32 w = x[t*8+i];
      u32 e = (w>>7)&0xFFu;
      c += (e==0u || (e>=96u && e<=143u)) ? 1 : 0;
    }
    atomicAdd(&cnt, c);
  }
  __syncthreads();
  const int f32 = (cnt < 1229) ? 1 : 0;     // 2048 words: bf16 ~2048, fp32 ~390
  if (blockIdx.x == 0 && blockIdx.y == 0 && t == 0) *flagp = f32;

  if (blockIdx.y == 2) {
    // convert wq (rows 0..255) | wkv (rows 256..767) -> Wqkv bf16
    int rbase = blockIdx.x * 12;            // 64 WGs x 12 rows = 768
    #pragma unroll
    for (int p=0;p<2;++p) {
      int rr = p*8 + (t>>5);                // 0..15
      int cg = (t&31)*8;                    // 0..248
      if (rr < 12) {
        int row = rbase + rr;
        uint4 w = (row < 256) ? ld8(wq, (size_t)row*256 + cg, f32)
                              : ld8(wkv, (size_t)(row-256)*256 + cg, f32);
        *(uint4*)&Wqkv[(size_t)row*256 + cg] = w;
      }
    }
    return;
  }

  const int o0 = blockIdx.x*16, c0 = blockIdx.y*128;
  {
    int row = t>>4, ch = (t&15)*16;
    *(uint4*)&WC[row*256+ch]     = ld8(wconv, (size_t)(o0+row)*256 + ch, f32);
    *(uint4*)&WC[row*256+ch+8]   = ld8(wconv, (size_t)(o0+row)*256 + ch + 8, f32);
  }
  float acc[8] = {};
  const int ty = t>>4, tx = t&15;
  for (int jc=0;jc<8;++jc) {
    __syncthreads();    // (jc=0: also covers WC staging) protect WO reuse
    {
      int jr = t>>3, cc = (t&7)*16;
      *(uint4*)&WO[jr*128+cc]   = ld8(wo, (size_t)(jc*32+jr)*256 + c0 + cc, f32);
      *(uint4*)&WO[jr*128+cc+8] = ld8(wo, (size_t)(jc*32+jr)*256 + c0 + cc + 8, f32);
    }
    __syncthreads();
    #pragma unroll 4
    for (int jj=0;jj<32;++jj) {
      float wv = bf2f(WC[ty*256 + jc*32 + jj]);
      short8 w8 = *(const short8*)&WO[jj*128 + tx*8];
      #pragma unroll
      for (int i=0;i<8;++i) acc[i] += wv * bf2f((u16)w8[i]);
    }
  }
  {
    u32 pw[4];
    #pragma unroll
    for (int j=0;j<4;++j) pw[j] = (u32)f2bf(acc[2*j]) | ((u32)f2bf(acc[2*j+1])<<16);
    *(uint4*)&F[(size_t)(o0+ty)*256 + c0 + tx*8] = *(uint4*)pw;
  }
  // parallel bias: b_fused[o] = sum_j wconv[o][j]*bo[j] + bconv[o]   (WC still resident)
  if (blockIdx.y == 0) {
    float s = 0.0f;
    #pragma unroll 4
    for (int j=tx*16; j<tx*16+16; ++j) s += bf2f(WC[ty*256+j]) * ldsc(bo, j, f32);
    bred[ty][tx] = s;
  }
  __syncthreads();
  if (blockIdx.y == 0 && t < 16) {
    float s = 0.0f;
    #pragma unroll
    for (int p=0;p<16;++p) s += bred[t][p];
    bfus[o0+t] = s + ldsc(bconv, o0+t, f32);
  }
}

// ---------------- K0: transpose x (B,C,HW) -> xt (B*HW, C), bf16 (fallback path) ----
__global__ __launch_bounds__(256) void k_transpose(const void* __restrict__ x, u16* __restrict__ xt,
                                                   const int* __restrict__ flagp)
{
  __shared__ int sflag;
  __shared__ __align__(16) u16 tile[64][68];
  if (threadIdx.x == 0) sflag = *flagp;
  __syncthreads();
  const int f32 = sflag;
  const int p0 = blockIdx.x*64, c0 = blockIdx.y*64, b = blockIdx.z;
  const int t = threadIdx.x;
  const size_t xbo = ((size_t)(b*256 + c0))*4096 + p0;
  #pragma unroll
  for (int pass=0; pass<4; ++pass) {
    int cl = pass*16 + (t>>4);
    int pl = (t&15)*4;
    uint2 v = ld4(x, xbo + (size_t)cl*4096 + pl, f32);
    *(uint2*)&tile[cl][pl] = v;
  }
  __syncthreads();
  u16* xtb = xt + ((size_t)b*4096 + p0)*256 + c0;
  #pragma unroll
  for (int pass=0; pass<4; ++pass) {
    int pl = pass*16 + (t>>4);
    int cl = (t&15)*4;
    unsigned int lo = (unsigned int)tile[cl][pl]   | ((unsigned int)tile[cl+1][pl]<<16);
    unsigned int hi = (unsigned int)tile[cl+2][pl] | ((unsigned int)tile[cl+3][pl]<<16);
    uint2 o; o.x = lo; o.y = hi;
    *(uint2*)(xtb + (size_t)pl*256 + cl) = o;
  }
}

// ------------- generic GEMM: C[M,N] = A[M,K] @ Bt[N,K]^T * colscale + bias --------------
// xpose=0: NO-LDS main loop, fragments direct from global (r7-proven).
// xpose=1: A is channel-major x (B,C,HW); A-tile staged to LDS [128px][40] with an
//          inline transpose. B must be an internal bf16 arena (internalB=1).
// swz=1: XCD-aware bijective remap (r9-proven: FETCH 35->13MB).
// Epilogues use LBAR (lgkm-only barrier): global stores from successive chunks stay
// in flight, raising per-CU store concurrency (the r9-identified wall).
// B split-routed (128-aligned nsplit; scale col<nsplit ? s_lo : s_hi).
// shuffle=1: PixelShuffle(2) epilogue, 4 chunks of 32 cols (r2-proven stores).
__global__ __launch_bounds__(256) void k_gemm_bt(
  const void* __restrict__ A, int lda,
  const void* __restrict__ Bt0, const void* __restrict__ Bt1, int nsplit,
  const void* __restrict__ bias,
  void* __restrict__ C, int M, int N, int K,
  float s_lo, float s_hi, int shuffle, int internalB, int xpose, int swz,
  const int* __restrict__ flagp)
{
  __shared__ int sflag;
  __shared__ __align__(16) char smem[18432];
  if (threadIdx.x == 0) sflag = *flagp;
  __syncthreads();
  const int f32 = sflag;
  const int bf = internalB ? 0 : f32;          // dtype of Bt loads
  const int biasf = internalB ? 1 : f32;       // dtype of bias loads
  int bx = blockIdx.x, by = blockIdx.y;
  if (swz) {
    int id  = by * gridDim.x + bx;
    int xcd = id & 7, idx = id >> 3;
    int ny  = gridDim.y, per = gridDim.x >> 3;
    bx = xcd * per + idx / ny;
    by = idx % ny;
  }
  const int m0 = bx*128, n0 = by*128;
  const void* Bs; int boff;
  if (Bt1 && n0 >= nsplit) { Bs = Bt1; boff = n0 - nsplit; } else { Bs = Bt0; boff = n0; }
  const int t = threadIdx.x, lane = t & 63, wv = t >> 6;
  const int wm = (wv & 1)*64, wn = (wv >> 1)*64;
  const int lm = lane & 15, lq = lane >> 4;
  f32x4 acc[4][4] = {};

  if (xpose) {
    // ---- A = x (channel-major), staged+transposed to LDS per K-step ----
    u16* Als = (u16*)smem;                    // 128 x 40 u16
    const int bb = m0 >> 12, px0 = m0 & 4095;
    const int ch = t & 31, pg = t >> 5;       // 32 ch x 8 px-groups
    const u16* Bq = (const u16*)Bs;
    for (int k0 = 0; k0 < K; k0 += 32) {
      if (k0) __syncthreads();                // prev frag reads done
      {
        size_t xo = ((size_t)(bb*256 + k0 + ch))*4096 + px0 + pg*16;
        u16 v[16];
        if (f32) {
          const float* fp = (const float*)A + xo;
          float4 q0 = *(const float4*)fp,     q1 = *(const float4*)(fp+4);
          float4 q2 = *(const float4*)(fp+8), q3 = *(const float4*)(fp+12);
          v[0]=f2bf(q0.x); v[1]=f2bf(q0.y); v[2]=f2bf(q0.z); v[3]=f2bf(q0.w);
          v[4]=f2bf(q1.x); v[5]=f2bf(q1.y); v[6]=f2bf(q1.z); v[7]=f2bf(q1.w);
          v[8]=f2bf(q2.x); v[9]=f2bf(q2.y); v[10]=f2bf(q2.z); v[11]=f2bf(q2.w);
          v[12]=f2bf(q3.x); v[13]=f2bf(q3.y); v[14]=f2bf(q3.z); v[15]=f2bf(q3.w);
        } else {
          const u16* hp = (const u16*)A + xo;
          *(uint4*)&v[0] = *(const uint4*)hp;
          *(uint4*)&v[8] = *(const uint4*)(hp+8);
        }
        #pragma unroll
        for (int j=0;j<16;++j) Als[(pg*16 + j)*40 + ch] = v[j];
      }
      __syncthreads();
      short8 af[4], bfr[4];
      #pragma unroll
      for (int i=0;i<4;++i) af[i] = *(const short8*)&Als[(wm + i*16 + lm)*40 + lq*8];
      #pragma unroll
      for (int i=0;i<4;++i) bfr[i] = *(const short8*)(Bq + (size_t)(boff + wn + i*16 + lm)*K + k0 + lq*8);
      #pragma unroll
      for (int mt=0;mt<4;++mt)
        #pragma unroll
        for (int nt=0;nt<4;++nt)
          acc[mt][nt] = MFMA16(af[mt], bfr[nt], acc[mt][nt]);
    }
  } else {
    // ---- NO-LDS main loop (r7-proven): fragments direct from global ----
    const u16* Au = (const u16*)A;
    const u16* arow[4];
    size_t brow[4];
    #pragma unroll
    for (int i=0;i<4;++i) {
      arow[i] = Au + (size_t)(m0 + wm + i*16 + lm)*lda + lq*8;
      brow[i] = (size_t)(boff + wn + i*16 + lm)*K + lq*8;
    }
    #pragma unroll 2
    for (int k0 = 0; k0 < K; k0 += 32) {
      short8 af[4], bfr[4];
      #pragma unroll
      for (int i=0;i<4;++i) af[i] = *(const short8*)(arow[i] + k0);
      #pragma unroll
      for (int i=0;i<4;++i) { uint4 v = ld8(Bs, brow[i] + k0, bf); bfr[i] = *(const short8*)&v; }
      #pragma unroll
      for (int mt=0;mt<4;++mt)
        #pragma unroll
        for (int nt=0;nt<4;++nt)
          acc[mt][nt] = MFMA16(af[mt], bfr[nt], acc[mt][nt]);
    }
  }

  if (!shuffle) {
    u16* eh = (u16*)smem;   // 128 x 72 u16 (18432B)
    #pragma unroll
    for (int c=0;c<2;++c) {
      LBAR;                                   // LDS-reuse fence; stores keep flying
      if ((wv>>1) == c) {
        #pragma unroll
        for (int nt=0;nt<4;++nt) {
          int col = n0 + c*64 + nt*16 + lm;
          float sc = (col < nsplit) ? s_lo : s_hi;
          float bv = bias ? ldsc(bias, col, biasf) : 0.0f;
          #pragma unroll
          for (int mt=0;mt<4;++mt)
            #pragma unroll
            for (int r=0;r<4;++r) {
              int row = wm + mt*16 + lq*4 + r;
              eh[row*72 + nt*16 + lm] = f2bf(acc[mt][nt][r]*sc + bv);
            }
        }
      }
      LBAR;
      {
        int row = t >> 1, off = (t & 1)*32;
        const uint4* s = (const uint4*)&eh[row*72 + off];
        uint4 v0 = s[0], v1 = s[1], v2 = s[2], v3 = s[3];
        uint4* dp = (uint4*)((u16*)C + (size_t)(m0+row)*N + n0 + c*64 + off);
        dp[0]=v0; dp[1]=v1; dp[2]=v2; dp[3]=v3;
      }
    }
  } else {
    // 4 chunks of 32 cols; ef = 32 output-rows x 134 fp32 (17152B)
    float* ef = (float*)smem;
    const int b = m0 >> 12;
    const int hh0 = (m0 & 4095) >> 6;   // tile = 2 image rows (hh0, hh0+1) x 64 px
    #pragma unroll
    for (int c=0;c<4;++c) {
      LBAR;                                   // LDS-reuse fence; stores keep flying
      if ((wv>>1) == (c>>1)) {
        #pragma unroll
        for (int nt2=0;nt2<2;++nt2) {
          int nt = (c&1)*2 + nt2;
          int col = n0 + wn + nt*16 + lm;             // global col
          float bv = bias ? ldsc(bias, col, biasf) : 0.0f;
          int col_rel = nt2*16 + lm;                  // 0..31 within chunk
          int cn_rel = col_rel >> 2, rr = (col_rel >> 1) & 1, ss = col_rel & 1;
          #pragma unroll
          for (int mt=0;mt<4;++mt)
            #pragma unroll
            for (int r=0;r<4;++r) {
              int row = wm + mt*16 + lq*4 + r;        // 0..127 (pixel within tile)
              int orow = cn_rel*4 + (row>>6)*2 + rr;  // output-row within chunk (0..31)
              int ow   = (row & 63)*2 + ss;           // 0..127
              ef[orow*134 + ow] = acc[mt][nt][r]*s_hi + bv;
            }
        }
      }
      LBAR;
      {
        int orow = t >> 3, seg = t & 7;               // 8 lanes cover one full 512B row
        int cn_rel = orow >> 2, oh_rel = orow & 3;
        int cn = ((n0 + c*32) >> 2) + cn_rel;
        size_t obase = (((size_t)(b*256 + cn))*128 + hh0*2 + oh_rel)*128 + seg*16;
        const float4* s = (const float4*)&ef[orow*134 + seg*16];
        float4 v0 = s[0], v1 = s[1], v2 = s[2], v3 = s[3];
        if (f32) {
          float4* dp = (float4*)((float*)C + obase);
          dp[0]=v0; dp[1]=v1; dp[2]=v2; dp[3]=v3;
        } else {
          float vv[16];
          *(float4*)&vv[0]=v0; *(float4*)&vv[4]=v1; *(float4*)&vv[8]=v2; *(float4*)&vv[12]=v3;
          u32 pw[8];
          #pragma unroll
          for (int j=0;j<8;++j) pw[j] = (u32)f2bf(vv[2*j]) | ((u32)f2bf(vv[2*j+1])<<16);
          u16* dp = (u16*)C + obase;
          *(uint4*)dp       = *(uint4*)&pw[0];
          *(uint4*)(dp + 8) = *(uint4*)&pw[4];
        }
      }
    }
  }
}

// ---------------- K2: halo attention, one WG per (block, head) ----------------
// Reads fused qkv buffer (stride 768: q | k | v); writes output to
// aout[p*ostride + head*64 + d] (ostride=256 for separate arena, 768 for in-place).
// swz=1: XCD-aware remap — each XCD owns one image (64 blocks x 4 heads).
#define MASKVAL (-30000.0f)
__global__ __launch_bounds__(256) void k_halo_attn(
  const u16* __restrict__ qkv,
  const void* __restrict__ relh, const void* __restrict__ relw,
  u16* __restrict__ aout, int ostride, int swz,
  const int* __restrict__ flagp)
{
  __shared__ int sflag;
  __shared__ __align__(16) u16 Qs[64*72];
  __shared__ __align__(16) u16 KP[128*72];
  __shared__ __align__(16) u16 Vt[64*136];
  __shared__ __align__(16) u16 Gw[64*32];
  __shared__ __align__(16) u16 Gh[64*32];
  if (threadIdx.x == 0) sflag = *flagp;
  __syncthreads();
  const int f32 = sflag;

  int blk = blockIdx.x, head = blockIdx.y;
  if (swz) {
    int id  = blockIdx.y * gridDim.x + blockIdx.x;
    int xcd = id & 7, idx = id >> 3;
    int per = gridDim.x >> 3;                 // blocks per xcd (=64)
    blk  = xcd * per + idx / gridDim.y;
    head = idx % gridDim.y;
  }
  const int bb = blk >> 6, by = (blk >> 3) & 7, bx = blk & 7;
  const int h0 = by*8, w0 = bx*8;
  const int t = threadIdx.x, lane = t & 63, wv = t >> 6;
  const int lm = lane & 15, lq = lane >> 4;
  const size_t pixbase = (size_t)bb * 4096;
  const float LOG2E = 1.4426950408889634f;

  #pragma unroll
  for (int i=0;i<2;++i) {
    int u = t + i*256;
    int row = u >> 3, ch = (u & 7)*8;
    int qx = row >> 3, qy = row & 7;
    size_t p = pixbase + (size_t)(h0+qx)*64 + (w0+qy);
    *(uint4*)&Qs[row*72 + ch] = *(const uint4*)(qkv + p*768 + head*64 + ch);
  }
  {
    u16* RW = KP; u16* RH = KP + 2048;
    if (t < 248) {
      *(uint4*)&RW[t*8] = ld8(relw, (size_t)t*8, f32);
      *(uint4*)&RH[t*8] = ld8(relh, (size_t)t*8, f32);
    } else {
      uint4 z; z.x=z.y=z.z=z.w=0;
      int o = 1984 + (t-248)*8;
      *(uint4*)&RW[o] = z;
      *(uint4*)&RH[o] = z;
    }
  }
  __syncthreads();
  {
    const u16* RW = KP; const u16* RH = KP + 2048;
    f32x4 agw[2] = {}, agh[2] = {};
    #pragma unroll
    for (int ks=0;ks<2;++ks) {
      short8 aq = *(const short8*)&Qs[(wv*16 + lm)*72 + ks*32 + lq*8];
      #pragma unroll
      for (int nt=0;nt<2;++nt) {
        short8 bw = *(const short8*)&RW[(nt*16 + lm)*64 + ks*32 + lq*8];
        short8 bh = *(const short8*)&RH[(nt*16 + lm)*64 + ks*32 + lq*8];
        agw[nt] = MFMA16(aq, bw, agw[nt]);
        agh[nt] = MFMA16(aq, bh, agh[nt]);
      }
    }
    #pragma unroll
    for (int nt=0;nt<2;++nt)
      #pragma unroll
      for (int r=0;r<4;++r) {
        int m = wv*16 + lq*4 + r, c = nt*16 + lm;
        Gw[m*32 + c] = f2bf(agw[nt][r]);
        Gh[m*32 + c] = f2bf(agh[nt][r]);
      }
  }
  __syncthreads();

  float m_run[4], l_run[4];
  #pragma unroll
  for (int r=0;r<4;++r){ m_run[r] = MASKVAL; l_run[r] = 0.0f; }
  f32x4 acc_o[4] = {};

  for (int tile=0; tile<2; ++tile) {
    #pragma unroll
    for (int i=0;i<4;++i) {
      int u = t + i*256;
      int kl = u >> 3, ch = (u & 7)*8;
      int ki = tile*8 + (kl >> 4), kj = kl & 15;
      int hk = h0 - 4 + ki, wk = w0 - 4 + kj;
      uint4 v; v.x=v.y=v.z=v.w=0;
      if ((unsigned)hk < 64u && (unsigned)wk < 64u) {
        size_t p = pixbase + (size_t)hk*64 + wk;
        v = *(const uint4*)(qkv + p*768 + 256 + head*64 + ch);
      }
      *(uint4*)&KP[kl*72 + ch] = v;
    }
    {
      int kl = t & 127, db = (t >> 7)*32;
      int ki = tile*8 + (kl >> 4), kj = kl & 15;
      int hk = h0 - 4 + ki, wk = w0 - 4 + kj;
      bool ok = ((unsigned)hk < 64u) && ((unsigned)wk < 64u);
      size_t p = pixbase + (size_t)hk*64 + wk;
      const u16* vp = qkv + p*768 + 512 + head*64 + db;
      #pragma unroll
      for (int c=0;c<4;++c) {
        union { uint4 v; u16 s[8]; } uu;
        uu.v.x=uu.v.y=uu.v.z=uu.v.w=0;
        if (ok) uu.v = *(const uint4*)(vp + c*8);
        #pragma unroll
        for (int jj=0;jj<8;++jj) Vt[(db + c*8 + jj)*136 + kl] = uu.s[jj];
      }
    }
    __syncthreads();
    f32x4 as[8] = {};
    #pragma unroll
    for (int ks=0;ks<2;++ks) {
      short8 aq = *(const short8*)&Qs[(wv*16 + lm)*72 + ks*32 + lq*8];
      #pragma unroll
      for (int nt=0;nt<8;++nt) {
        short8 bk = *(const short8*)&KP[(nt*16 + lm)*72 + ks*32 + lq*8];
        as[nt] = MFMA16(aq, bk, as[nt]);
      }
    }
    __syncthreads();
    #pragma unroll
    for (int r=0;r<4;++r) {
      int m = wv*16 + lq*4 + r;
      int qx = m >> 3, qy = m & 7;
      float vals[8]; float rowmax = MASKVAL;
      #pragma unroll
      for (int nt=0;nt<8;++nt) {
        int ki = tile*8 + nt;
        int hk = h0 - 4 + ki, wk = w0 - 4 + lm;
        float v = as[nt][r]
                + bf2f(Gw[m*32 + (lm - qy + 15)])
                + bf2f(Gh[m*32 + (ki - qx + 15)]);
        if (!((unsigned)hk < 64u && (unsigned)wk < 64u)) v = MASKVAL;
        vals[nt] = v;
        rowmax = fmaxf(rowmax, v);
      }
      #pragma unroll
      for (int s=1;s<16;s<<=1) rowmax = fmaxf(rowmax, __shfl_xor(rowmax, s, 64));
      float mnew = fmaxf(m_run[r], rowmax);
      float alpha = exp2f((m_run[r] - mnew)*LOG2E);
      float rs = 0.0f;
      #pragma unroll
      for (int nt=0;nt<8;++nt) {
        float e = exp2f((vals[nt] - mnew)*LOG2E);
        rs += e;
        KP[m*136 + nt*16 + lm] = f2bf(e);
      }
      #pragma unroll
      for (int s=1;s<16;s<<=1) rs += __shfl_xor(rs, s, 64);
      l_run[r] = l_run[r]*alpha + rs;
      m_run[r] = mnew;
      #pragma unroll
      for (int nt=0;nt<4;++nt) acc_o[nt][r] *= alpha;
    }
    __syncthreads();
    #pragma unroll
    for (int ks=0;ks<4;++ks) {
      short8 ap = *(const short8*)&KP[(wv*16 + lm)*136 + ks*32 + lq*8];
      #pragma unroll
      for (int nt=0;nt<4;++nt) {
        short8 bv = *(const short8*)&Vt[(nt*16 + lm)*136 + ks*32 + lq*8];
        acc_o[nt] = MFMA16(ap, bv, acc_o[nt]);
      }
    }
    __syncthreads();
  }
  #pragma unroll
  for (int nt=0;nt<4;++nt)
    #pragma unroll
    for (int r=0;r<4;++r) {
      int m = wv*16 + lq*4 + r;
      int qx = m >> 3, qy = m & 7;
      size_t p = pixbase + (size_t)(h0+qx)*64 + (w0+qy);
      aout[p*(size_t)ostride + head*64 + nt*16 + lm] = f2bf(acc_o[nt][r]/l_run[r]);
    }
}

extern "C" void kernel_launch(void* const* d_in, const int* in_sizes, int n_in,
                              void* d_out, int out_size, void* d_ws, size_t ws_size,
                              hipStream_t stream)
{
  const void* x     = d_in[0];
  const void* wq    = d_in[1];
  const void* wkv   = d_in[2];
  const void* wo    = d_in[3];
  const void* bo    = d_in[4];
  const void* relh  = d_in[5];
  const void* relw  = d_in[6];
  const void* wconv = d_in[7];
  const void* bconv = d_in[8];

  int*  flag = (int*)d_ws;
  u16*  base = (u16*)d_out;
  u16*  qkv  = base;                            // 32768 x 768 bf16 (q | k | v)
  u16*  xt   = base + 25165824;                 // 32768 x 256 bf16 (fallback only)

  const size_t WS_FUSED = 4096 + 524288 + 4096 + 16777216;  // flag|Wf|bf|aout

  if (ws_size >= WS_FUSED) {
    // ---- fused path: wo folded into conv; weights pre-converted; transpose inline ----
    u16*   Wf   = (u16*)((char*)d_ws + 4096);
    float* bfus = (float*)((char*)d_ws + 4096 + 524288);
    u16*   aout = (u16*)((char*)d_ws + 4096 + 524288 + 4096);
    u16*   Wqkv = aout;    // 768x256 bf16 (393KB) in aout region; dead before attn writes
    k_fuse_w<<<dim3(64,3), 256, 0, stream>>>((const u32*)x, wq, wkv, wo, wconv, bo, bconv,
                                             Wf, bfus, Wqkv, flag);
    // qkv projection straight from x (inline transpose), bf16 weights, XCD swizzle
    k_gemm_bt<<<dim3(256,6), 256, 0, stream>>>(x, 0, Wqkv, nullptr, 256, nullptr,
                                               qkv, 32768, 768, 256, 0.125f, 1.0f, 0, 1, 1, 1, flag);
    k_halo_attn<<<dim3(512,4), 256, 0, stream>>>(qkv, relh, relw, aout, 256, 1, flag);
    k_gemm_bt<<<dim3(256,8), 256, 0, stream>>>(aout, 256, Wf, nullptr, 0, bfus,
                                               d_out, 32768, 1024, 256, 1.0f, 1.0f, 1, 1, 0, 1, flag);
  } else {
    // ---- fallback (r2 pipeline): separate transpose + wo-GEMM through y2 in ws ----
    u16* y2 = (u16*)((char*)d_ws + 4096);
    k_detect<<<1, 256, 0, stream>>>((const u32*)x, flag);
    k_transpose<<<dim3(64,4,8), 256, 0, stream>>>(x, xt, flag);
    k_gemm_bt<<<dim3(256,6), 256, 0, stream>>>(xt, 256, wq, wkv, 256, nullptr,
                                               qkv, 32768, 768, 256, 0.125f, 1.0f, 0, 0, 0, 0, flag);
    k_halo_attn<<<dim3(512,4), 256, 0, stream>>>(qkv, relh, relw, qkv, 768, 0, flag);
    k_gemm_bt<<<dim3(256,2), 256, 0, stream>>>(qkv, 768, wo, nullptr, 0, bo,
                                               y2, 32768, 256, 256, 1.0f, 1.0f, 0, 0, 0, 0, flag);
    k_gemm_bt<<<dim3(256,8), 256, 0, stream>>>(y2, 256, wconv, nullptr, 0, bconv,
                                               d_out, 32768, 1024, 256, 1.0f, 1.0f, 1, 0, 0, 0, flag);
  }
}

// Round 12
// 364.833 us; speedup vs baseline: 1.1170x; 1.0022x over previous
//
#include <hip/hip_runtime.h>

typedef unsigned short u16;
typedef unsigned int u32;
typedef __attribute__((ext_vector_type(8))) short short8;
typedef __attribute__((ext_vector_type(4))) float f32x4;

__device__ __forceinline__ float bf2f(u16 u){ union { u32 i; float f; } x; x.i = ((u32)u)<<16; return x.f; }
__device__ __forceinline__ u16 f2bf(float f){ union { float f; u32 i; } x; x.f = f; u32 r = x.i + 0x7fffu + ((x.i>>16)&1u); return (u16)(r>>16); }

#define MFMA16(a,b,c) __builtin_amdgcn_mfma_f32_16x16x32_bf16((a),(b),(c),0,0,0)

// ---- dual-dtype external loads: fp32 inputs are converted to bf16 at ingest ----
__device__ __forceinline__ uint4 ld8(const void* p, size_t off, int f32) {
  if (f32) {
    const float* fp = (const float*)p + off;
    float4 a = *(const float4*)fp;
    float4 b = *(const float4*)(fp + 4);
    uint4 o;
    o.x = (u32)f2bf(a.x) | ((u32)f2bf(a.y)<<16);
    o.y = (u32)f2bf(a.z) | ((u32)f2bf(a.w)<<16);
    o.z = (u32)f2bf(b.x) | ((u32)f2bf(b.y)<<16);
    o.w = (u32)f2bf(b.z) | ((u32)f2bf(b.w)<<16);
    return o;
  }
  return *(const uint4*)((const u16*)p + off);
}
__device__ __forceinline__ uint2 ld4(const void* p, size_t off, int f32) {
  if (f32) {
    const float* fp = (const float*)p + off;
    float4 a = *(const float4*)fp;
    uint2 o;
    o.x = (u32)f2bf(a.x) | ((u32)f2bf(a.y)<<16);
    o.y = (u32)f2bf(a.z) | ((u32)f2bf(a.w)<<16);
    return o;
  }
  return *(const uint2*)((const u16*)p + off);
}
__device__ __forceinline__ float ldsc(const void* p, size_t off, int f32) {
  if (f32) return ((const float*)p)[off];
  return bf2f(((const u16*)p)[off]);
}

// ---- K-1: detect input dtype from x's low 16 bits (bf16 exponent vs fp32 mantissa) ----
__global__ __launch_bounds__(256) void k_detect(const u32* __restrict__ x, int* __restrict__ flag)
{
  __shared__ int cnt;
  if (threadIdx.x == 0) cnt = 0;
  __syncthreads();
  int c = 0;
  #pragma unroll
  for (int i = 0; i < 32; ++i) {
    u32 w = x[threadIdx.x*32 + i];
    u32 e = (w >> 7) & 0xFFu;
    c += (e == 0u || (e >= 96u && e <= 143u)) ? 1 : 0;
  }
  atomicAdd(&cnt, c);
  __syncthreads();
  if (threadIdx.x == 0) *flag = (cnt < 4915) ? 1 : 0;
}

// ---- K-fuse: y=0,1: W_fused = wconv @ wo (bf16) + b_fused; y=2: convert wq|wkv
// to bf16 arena Wqkv[768][256]. All WGs do a local dtype vote; WG(0,0) publishes.
__global__ __launch_bounds__(256) void k_fuse_w(
  const u32* __restrict__ x,
  const void* __restrict__ wq, const void* __restrict__ wkv,
  const void* __restrict__ wo, const void* __restrict__ wconv,
  const void* __restrict__ bo, const void* __restrict__ bconv,
  u16* __restrict__ F, float* __restrict__ bfus, u16* __restrict__ Wqkv,
  int* __restrict__ flagp)
{
  __shared__ int cnt;
  __shared__ __align__(16) u16 WC[16*256];   // wconv o-block, bf16
  __shared__ __align__(16) u16 WO[32*128];   // wo j-chunk x c-half, bf16
  __shared__ float bred[16][17];
  const int t = threadIdx.x;
  if (t == 0) cnt = 0;
  __syncthreads();
  {
    int c = 0;
    #pragma unroll
    for (int i=0;i<8;++i) {
      u32 w = x[t*8+i];
      u32 e = (w>>7)&0xFFu;
      c += (e==0u || (e>=96u && e<=143u)) ? 1 : 0;
    }
    atomicAdd(&cnt, c);
  }
  __syncthreads();
  const int f32 = (cnt < 1229) ? 1 : 0;     // 2048 words: bf16 ~2048, fp32 ~390
  if (blockIdx.x == 0 && blockIdx.y == 0 && t == 0) *flagp = f32;

  if (blockIdx.y == 2) {
    // convert wq (rows 0..255) | wkv (rows 256..767) -> Wqkv bf16
    int rbase = blockIdx.x * 12;            // 64 WGs x 12 rows = 768
    #pragma unroll
    for (int p=0;p<2;++p) {
      int rr = p*8 + (t>>5);                // 0..15
      int cg = (t&31)*8;                    // 0..248
      if (rr < 12) {
        int row = rbase + rr;
        uint4 w = (row < 256) ? ld8(wq, (size_t)row*256 + cg, f32)
                              : ld8(wkv, (size_t)(row-256)*256 + cg, f32);
        *(uint4*)&Wqkv[(size_t)row*256 + cg] = w;
      }
    }
    return;
  }

  const int o0 = blockIdx.x*16, c0 = blockIdx.y*128;
  {
    int row = t>>4, ch = (t&15)*16;
    *(uint4*)&WC[row*256+ch]     = ld8(wconv, (size_t)(o0+row)*256 + ch, f32);
    *(uint4*)&WC[row*256+ch+8]   = ld8(wconv, (size_t)(o0+row)*256 + ch + 8, f32);
  }
  float acc[8] = {};
  const int ty = t>>4, tx = t&15;
  for (int jc=0;jc<8;++jc) {
    __syncthreads();    // (jc=0: also covers WC staging) protect WO reuse
    {
      int jr = t>>3, cc = (t&7)*16;
      *(uint4*)&WO[jr*128+cc]   = ld8(wo, (size_t)(jc*32+jr)*256 + c0 + cc, f32);
      *(uint4*)&WO[jr*128+cc+8] = ld8(wo, (size_t)(jc*32+jr)*256 + c0 + cc + 8, f32);
    }
    __syncthreads();
    #pragma unroll 4
    for (int jj=0;jj<32;++jj) {
      float wv = bf2f(WC[ty*256 + jc*32 + jj]);
      short8 w8 = *(const short8*)&WO[jj*128 + tx*8];
      #pragma unroll
      for (int i=0;i<8;++i) acc[i] += wv * bf2f((u16)w8[i]);
    }
  }
  {
    u32 pw[4];
    #pragma unroll
    for (int j=0;j<4;++j) pw[j] = (u32)f2bf(acc[2*j]) | ((u32)f2bf(acc[2*j+1])<<16);
    *(uint4*)&F[(size_t)(o0+ty)*256 + c0 + tx*8] = *(uint4*)pw;
  }
  // parallel bias: b_fused[o] = sum_j wconv[o][j]*bo[j] + bconv[o]   (WC still resident)
  if (blockIdx.y == 0) {
    float s = 0.0f;
    #pragma unroll 4
    for (int j=tx*16; j<tx*16+16; ++j) s += bf2f(WC[ty*256+j]) * ldsc(bo, j, f32);
    bred[ty][tx] = s;
  }
  __syncthreads();
  if (blockIdx.y == 0 && t < 16) {
    float s = 0.0f;
    #pragma unroll
    for (int p=0;p<16;++p) s += bred[t][p];
    bfus[o0+t] = s + ldsc(bconv, o0+t, f32);
  }
}

// ---------------- K0: transpose x (B,C,HW) -> xt (B*HW, C), bf16 (fallback path) ----
__global__ __launch_bounds__(256) void k_transpose(const void* __restrict__ x, u16* __restrict__ xt,
                                                   const int* __restrict__ flagp)
{
  __shared__ int sflag;
  __shared__ __align__(16) u16 tile[64][68];
  if (threadIdx.x == 0) sflag = *flagp;
  __syncthreads();
  const int f32 = sflag;
  const int p0 = blockIdx.x*64, c0 = blockIdx.y*64, b = blockIdx.z;
  const int t = threadIdx.x;
  const size_t xbo = ((size_t)(b*256 + c0))*4096 + p0;
  #pragma unroll
  for (int pass=0; pass<4; ++pass) {
    int cl = pass*16 + (t>>4);
    int pl = (t&15)*4;
    uint2 v = ld4(x, xbo + (size_t)cl*4096 + pl, f32);
    *(uint2*)&tile[cl][pl] = v;
  }
  __syncthreads();
  u16* xtb = xt + ((size_t)b*4096 + p0)*256 + c0;
  #pragma unroll
  for (int pass=0; pass<4; ++pass) {
    int pl = pass*16 + (t>>4);
    int cl = (t&15)*4;
    unsigned int lo = (unsigned int)tile[cl][pl]   | ((unsigned int)tile[cl+1][pl]<<16);
    unsigned int hi = (unsigned int)tile[cl+2][pl] | ((unsigned int)tile[cl+3][pl]<<16);
    uint2 o; o.x = lo; o.y = hi;
    *(uint2*)(xtb + (size_t)pl*256 + cl) = o;
  }
}

// ------------- generic GEMM: C[M,N] = A[M,K] @ Bt[N,K]^T * colscale + bias --------------
// TEMPLATE-SPECIALIZED on host-known flags (SHUF/IB/XP/SWZ): with IB=1 the main loop
// is fully branch-free (pure uint4 loads, one scheduling region -> loads batch).
// Only the data dtype flag (f32, device-detected) stays runtime, confined to x-staging
// and the store path.
// XP=0: NO-LDS main loop, fragments direct from global (r7-proven).
// XP=1: A is channel-major x (B,C,HW); A-tile staged to LDS [128px][40] inline-transposed.
// SWZ=1: XCD-aware bijective remap (r9-proven: FETCH 35->13MB).
template<int SHUF, int IB, int XP, int SWZ>
__global__ __launch_bounds__(256) void k_gemm_bt(
  const void* __restrict__ A, int lda,
  const void* __restrict__ Bt0, const void* __restrict__ Bt1, int nsplit,
  const void* __restrict__ bias,
  void* __restrict__ C, int M, int N, int K,
  float s_lo, float s_hi,
  const int* __restrict__ flagp)
{
  __shared__ int sflag;
  __shared__ __align__(16) char smem[18432];
  if (threadIdx.x == 0) sflag = *flagp;
  __syncthreads();
  const int f32 = sflag;
  const int bf = IB ? 0 : f32;                 // compile-time 0 when IB=1
  const int biasf = IB ? 1 : f32;
  int bx = blockIdx.x, by = blockIdx.y;
  if (SWZ) {
    int id  = by * gridDim.x + bx;
    int xcd = id & 7, idx = id >> 3;
    int ny  = gridDim.y, per = gridDim.x >> 3;
    bx = xcd * per + idx / ny;
    by = idx % ny;
  }
  const int m0 = bx*128, n0 = by*128;
  const void* Bs; int boff;
  if (Bt1 && n0 >= nsplit) { Bs = Bt1; boff = n0 - nsplit; } else { Bs = Bt0; boff = n0; }
  const int t = threadIdx.x, lane = t & 63, wv = t >> 6;
  const int wm = (wv & 1)*64, wn = (wv >> 1)*64;
  const int lm = lane & 15, lq = lane >> 4;
  f32x4 acc[4][4] = {};

  if (XP) {
    // ---- A = x (channel-major), staged+transposed to LDS per K-step ----
    u16* Als = (u16*)smem;                    // 128 x 40 u16
    const int bb = m0 >> 12, px0 = m0 & 4095;
    const int ch = t & 31, pg = t >> 5;       // 32 ch x 8 px-groups
    const u16* Bq = (const u16*)Bs;
    for (int k0 = 0; k0 < K; k0 += 32) {
      if (k0) __syncthreads();                // prev frag reads done
      {
        size_t xo = ((size_t)(bb*256 + k0 + ch))*4096 + px0 + pg*16;
        u16 v[16];
        if (f32) {
          const float* fp = (const float*)A + xo;
          float4 q0 = *(const float4*)fp,     q1 = *(const float4*)(fp+4);
          float4 q2 = *(const float4*)(fp+8), q3 = *(const float4*)(fp+12);
          v[0]=f2bf(q0.x); v[1]=f2bf(q0.y); v[2]=f2bf(q0.z); v[3]=f2bf(q0.w);
          v[4]=f2bf(q1.x); v[5]=f2bf(q1.y); v[6]=f2bf(q1.z); v[7]=f2bf(q1.w);
          v[8]=f2bf(q2.x); v[9]=f2bf(q2.y); v[10]=f2bf(q2.z); v[11]=f2bf(q2.w);
          v[12]=f2bf(q3.x); v[13]=f2bf(q3.y); v[14]=f2bf(q3.z); v[15]=f2bf(q3.w);
        } else {
          const u16* hp = (const u16*)A + xo;
          *(uint4*)&v[0] = *(const uint4*)hp;
          *(uint4*)&v[8] = *(const uint4*)(hp+8);
        }
        #pragma unroll
        for (int j=0;j<16;++j) Als[(pg*16 + j)*40 + ch] = v[j];
      }
      __syncthreads();
      short8 af[4], bfr[4];
      #pragma unroll
      for (int i=0;i<4;++i) af[i] = *(const short8*)&Als[(wm + i*16 + lm)*40 + lq*8];
      #pragma unroll
      for (int i=0;i<4;++i) bfr[i] = *(const short8*)(Bq + (size_t)(boff + wn + i*16 + lm)*K + k0 + lq*8);
      #pragma unroll
      for (int mt=0;mt<4;++mt)
        #pragma unroll
        for (int nt=0;nt<4;++nt)
          acc[mt][nt] = MFMA16(af[mt], bfr[nt], acc[mt][nt]);
    }
  } else {
    // ---- NO-LDS main loop (r7-proven): fragments direct from global ----
    const u16* Au = (const u16*)A;
    const u16* arow[4];
    size_t brow[4];
    #pragma unroll
    for (int i=0;i<4;++i) {
      arow[i] = Au + (size_t)(m0 + wm + i*16 + lm)*lda + lq*8;
      brow[i] = (size_t)(boff + wn + i*16 + lm)*K + lq*8;
    }
    #pragma unroll 2
    for (int k0 = 0; k0 < K; k0 += 32) {
      short8 af[4], bfr[4];
      #pragma unroll
      for (int i=0;i<4;++i) af[i] = *(const short8*)(arow[i] + k0);
      #pragma unroll
      for (int i=0;i<4;++i) { uint4 v = ld8(Bs, brow[i] + k0, bf); bfr[i] = *(const short8*)&v; }
      #pragma unroll
      for (int mt=0;mt<4;++mt)
        #pragma unroll
        for (int nt=0;nt<4;++nt)
          acc[mt][nt] = MFMA16(af[mt], bfr[nt], acc[mt][nt]);
    }
  }

  if (!SHUF) {
    u16* eh = (u16*)smem;   // 128 x 72 u16 (18432B)
    #pragma unroll
    for (int c=0;c<2;++c) {
      __syncthreads();
      if ((wv>>1) == c) {
        #pragma unroll
        for (int nt=0;nt<4;++nt) {
          int col = n0 + c*64 + nt*16 + lm;
          float sc = (col < nsplit) ? s_lo : s_hi;
          float bv = bias ? ldsc(bias, col, biasf) : 0.0f;
          #pragma unroll
          for (int mt=0;mt<4;++mt)
            #pragma unroll
            for (int r=0;r<4;++r) {
              int row = wm + mt*16 + lq*4 + r;
              eh[row*72 + nt*16 + lm] = f2bf(acc[mt][nt][r]*sc + bv);
            }
        }
      }
      __syncthreads();
      {
        int row = t >> 1, off = (t & 1)*32;
        const uint4* s = (const uint4*)&eh[row*72 + off];
        uint4 v0 = s[0], v1 = s[1], v2 = s[2], v3 = s[3];
        uint4* dp = (uint4*)((u16*)C + (size_t)(m0+row)*N + n0 + c*64 + off);
        dp[0]=v0; dp[1]=v1; dp[2]=v2; dp[3]=v3;
      }
    }
  } else {
    // 4 chunks of 32 cols; ef = 32 output-rows x 134 fp32 (17152B)
    float* ef = (float*)smem;
    const int b = m0 >> 12;
    const int hh0 = (m0 & 4095) >> 6;   // tile = 2 image rows (hh0, hh0+1) x 64 px
    #pragma unroll
    for (int c=0;c<4;++c) {
      __syncthreads();
      if ((wv>>1) == (c>>1)) {
        #pragma unroll
        for (int nt2=0;nt2<2;++nt2) {
          int nt = (c&1)*2 + nt2;
          int col = n0 + wn + nt*16 + lm;             // global col
          float bv = bias ? ldsc(bias, col, biasf) : 0.0f;
          int col_rel = nt2*16 + lm;                  // 0..31 within chunk
          int cn_rel = col_rel >> 2, rr = (col_rel >> 1) & 1, ss = col_rel & 1;
          #pragma unroll
          for (int mt=0;mt<4;++mt)
            #pragma unroll
            for (int r=0;r<4;++r) {
              int row = wm + mt*16 + lq*4 + r;        // 0..127 (pixel within tile)
              int orow = cn_rel*4 + (row>>6)*2 + rr;  // output-row within chunk (0..31)
              int ow   = (row & 63)*2 + ss;           // 0..127
              ef[orow*134 + ow] = acc[mt][nt][r]*s_hi + bv;
            }
        }
      }
      __syncthreads();
      {
        int orow = t >> 3, seg = t & 7;               // 8 lanes cover one full 512B row
        int cn_rel = orow >> 2, oh_rel = orow & 3;
        int cn = ((n0 + c*32) >> 2) + cn_rel;
        size_t obase = (((size_t)(b*256 + cn))*128 + hh0*2 + oh_rel)*128 + seg*16;
        const float4* s = (const float4*)&ef[orow*134 + seg*16];
        float4 v0 = s[0], v1 = s[1], v2 = s[2], v3 = s[3];
        if (f32) {
          float4* dp = (float4*)((float*)C + obase);
          dp[0]=v0; dp[1]=v1; dp[2]=v2; dp[3]=v3;
        } else {
          float vv[16];
          *(float4*)&vv[0]=v0; *(float4*)&vv[4]=v1; *(float4*)&vv[8]=v2; *(float4*)&vv[12]=v3;
          u32 pw[8];
          #pragma unroll
          for (int j=0;j<8;++j) pw[j] = (u32)f2bf(vv[2*j]) | ((u32)f2bf(vv[2*j+1])<<16);
          u16* dp = (u16*)C + obase;
          *(uint4*)dp       = *(uint4*)&pw[0];
          *(uint4*)(dp + 8) = *(uint4*)&pw[4];
        }
      }
    }
  }
}

// ---------------- K2: halo attention, one WG per (block, head) ----------------
// Reads fused qkv buffer (stride 768: q | k | v); writes output to
// aout[p*ostride + head*64 + d]. SWZ=1: each XCD owns one image (64 blocks x 4 heads).
#define MASKVAL (-30000.0f)
template<int SWZ>
__global__ __launch_bounds__(256) void k_halo_attn(
  const u16* __restrict__ qkv,
  const void* __restrict__ relh, const void* __restrict__ relw,
  u16* __restrict__ aout, int ostride,
  const int* __restrict__ flagp)
{
  __shared__ int sflag;
  __shared__ __align__(16) u16 Qs[64*72];
  __shared__ __align__(16) u16 KP[128*72];
  __shared__ __align__(16) u16 Vt[64*136];
  __shared__ __align__(16) u16 Gw[64*32];
  __shared__ __align__(16) u16 Gh[64*32];
  if (threadIdx.x == 0) sflag = *flagp;
  __syncthreads();
  const int f32 = sflag;

  int blk = blockIdx.x, head = blockIdx.y;
  if (SWZ) {
    int id  = blockIdx.y * gridDim.x + blockIdx.x;
    int xcd = id & 7, idx = id >> 3;
    int per = gridDim.x >> 3;                 // blocks per xcd (=64)
    blk  = xcd * per + idx / gridDim.y;
    head = idx % gridDim.y;
  }
  const int bb = blk >> 6, by = (blk >> 3) & 7, bx = blk & 7;
  const int h0 = by*8, w0 = bx*8;
  const int t = threadIdx.x, lane = t & 63, wv = t >> 6;
  const int lm = lane & 15, lq = lane >> 4;
  const size_t pixbase = (size_t)bb * 4096;
  const float LOG2E = 1.4426950408889634f;

  #pragma unroll
  for (int i=0;i<2;++i) {
    int u = t + i*256;
    int row = u >> 3, ch = (u & 7)*8;
    int qx = row >> 3, qy = row & 7;
    size_t p = pixbase + (size_t)(h0+qx)*64 + (w0+qy);
    *(uint4*)&Qs[row*72 + ch] = *(const uint4*)(qkv + p*768 + head*64 + ch);
  }
  {
    u16* RW = KP; u16* RH = KP + 2048;
    if (t < 248) {
      *(uint4*)&RW[t*8] = ld8(relw, (size_t)t*8, f32);
      *(uint4*)&RH[t*8] = ld8(relh, (size_t)t*8, f32);
    } else {
      uint4 z; z.x=z.y=z.z=z.w=0;
      int o = 1984 + (t-248)*8;
      *(uint4*)&RW[o] = z;
      *(uint4*)&RH[o] = z;
    }
  }
  __syncthreads();
  {
    const u16* RW = KP; const u16* RH = KP + 2048;
    f32x4 agw[2] = {}, agh[2] = {};
    #pragma unroll
    for (int ks=0;ks<2;++ks) {
      short8 aq = *(const short8*)&Qs[(wv*16 + lm)*72 + ks*32 + lq*8];
      #pragma unroll
      for (int nt=0;nt<2;++nt) {
        short8 bw = *(const short8*)&RW[(nt*16 + lm)*64 + ks*32 + lq*8];
        short8 bh = *(const short8*)&RH[(nt*16 + lm)*64 + ks*32 + lq*8];
        agw[nt] = MFMA16(aq, bw, agw[nt]);
        agh[nt] = MFMA16(aq, bh, agh[nt]);
      }
    }
    #pragma unroll
    for (int nt=0;nt<2;++nt)
      #pragma unroll
      for (int r=0;r<4;++r) {
        int m = wv*16 + lq*4 + r, c = nt*16 + lm;
        Gw[m*32 + c] = f2bf(agw[nt][r]);
        Gh[m*32 + c] = f2bf(agh[nt][r]);
      }
  }
  __syncthreads();

  float m_run[4], l_run[4];
  #pragma unroll
  for (int r=0;r<4;++r){ m_run[r] = MASKVAL; l_run[r] = 0.0f; }
  f32x4 acc_o[4] = {};

  for (int tile=0; tile<2; ++tile) {
    #pragma unroll
    for (int i=0;i<4;++i) {
      int u = t + i*256;
      int kl = u >> 3, ch = (u & 7)*8;
      int ki = tile*8 + (kl >> 4), kj = kl & 15;
      int hk = h0 - 4 + ki, wk = w0 - 4 + kj;
      uint4 v; v.x=v.y=v.z=v.w=0;
      if ((unsigned)hk < 64u && (unsigned)wk < 64u) {
        size_t p = pixbase + (size_t)hk*64 + wk;
        v = *(const uint4*)(qkv + p*768 + 256 + head*64 + ch);
      }
      *(uint4*)&KP[kl*72 + ch] = v;
    }
    {
      int kl = t & 127, db = (t >> 7)*32;
      int ki = tile*8 + (kl >> 4), kj = kl & 15;
      int hk = h0 - 4 + ki, wk = w0 - 4 + kj;
      bool ok = ((unsigned)hk < 64u) && ((unsigned)wk < 64u);
      size_t p = pixbase + (size_t)hk*64 + wk;
      const u16* vp = qkv + p*768 + 512 + head*64 + db;
      #pragma unroll
      for (int c=0;c<4;++c) {
        union { uint4 v; u16 s[8]; } uu;
        uu.v.x=uu.v.y=uu.v.z=uu.v.w=0;
        if (ok) uu.v = *(const uint4*)(vp + c*8);
        #pragma unroll
        for (int jj=0;jj<8;++jj) Vt[(db + c*8 + jj)*136 + kl] = uu.s[jj];
      }
    }
    __syncthreads();
    f32x4 as[8] = {};
    #pragma unroll
    for (int ks=0;ks<2;++ks) {
      short8 aq = *(const short8*)&Qs[(wv*16 + lm)*72 + ks*32 + lq*8];
      #pragma unroll
      for (int nt=0;nt<8;++nt) {
        short8 bk = *(const short8*)&KP[(nt*16 + lm)*72 + ks*32 + lq*8];
        as[nt] = MFMA16(aq, bk, as[nt]);
      }
    }
    __syncthreads();
    #pragma unroll
    for (int r=0;r<4;++r) {
      int m = wv*16 + lq*4 + r;
      int qx = m >> 3, qy = m & 7;
      float vals[8]; float rowmax = MASKVAL;
      #pragma unroll
      for (int nt=0;nt<8;++nt) {
        int ki = tile*8 + nt;
        int hk = h0 - 4 + ki, wk = w0 - 4 + lm;
        float v = as[nt][r]
                + bf2f(Gw[m*32 + (lm - qy + 15)])
                + bf2f(Gh[m*32 + (ki - qx + 15)]);
        if (!((unsigned)hk < 64u && (unsigned)wk < 64u)) v = MASKVAL;
        vals[nt] = v;
        rowmax = fmaxf(rowmax, v);
      }
      #pragma unroll
      for (int s=1;s<16;s<<=1) rowmax = fmaxf(rowmax, __shfl_xor(rowmax, s, 64));
      float mnew = fmaxf(m_run[r], rowmax);
      float alpha = exp2f((m_run[r] - mnew)*LOG2E);
      float rs = 0.0f;
      #pragma unroll
      for (int nt=0;nt<8;++nt) {
        float e = exp2f((vals[nt] - mnew)*LOG2E);
        rs += e;
        KP[m*136 + nt*16 + lm] = f2bf(e);
      }
      #pragma unroll
      for (int s=1;s<16;s<<=1) rs += __shfl_xor(rs, s, 64);
      l_run[r] = l_run[r]*alpha + rs;
      m_run[r] = mnew;
      #pragma unroll
      for (int nt=0;nt<4;++nt) acc_o[nt][r] *= alpha;
    }
    __syncthreads();
    #pragma unroll
    for (int ks=0;ks<4;++ks) {
      short8 ap = *(const short8*)&KP[(wv*16 + lm)*136 + ks*32 + lq*8];
      #pragma unroll
      for (int nt=0;nt<4;++nt) {
        short8 bv = *(const short8*)&Vt[(nt*16 + lm)*136 + ks*32 + lq*8];
        acc_o[nt] = MFMA16(ap, bv, acc_o[nt]);
      }
    }
    __syncthreads();
  }
  #pragma unroll
  for (int nt=0;nt<4;++nt)
    #pragma unroll
    for (int r=0;r<4;++r) {
      int m = wv*16 + lq*4 + r;
      int qx = m >> 3, qy = m & 7;
      size_t p = pixbase + (size_t)(h0+qx)*64 + (w0+qy);
      aout[p*(size_t)ostride + head*64 + nt*16 + lm] = f2bf(acc_o[nt][r]/l_run[r]);
    }
}

extern "C" void kernel_launch(void* const* d_in, const int* in_sizes, int n_in,
                              void* d_out, int out_size, void* d_ws, size_t ws_size,
                              hipStream_t stream)
{
  const void* x     = d_in[0];
  const void* wq    = d_in[1];
  const void* wkv   = d_in[2];
  const void* wo    = d_in[3];
  const void* bo    = d_in[4];
  const void* relh  = d_in[5];
  const void* relw  = d_in[6];
  const void* wconv = d_in[7];
  const void* bconv = d_in[8];

  int*  flag = (int*)d_ws;
  u16*  base = (u16*)d_out;
  u16*  qkv  = base;                            // 32768 x 768 bf16 (q | k | v)
  u16*  xt   = base + 25165824;                 // 32768 x 256 bf16 (fallback only)

  const size_t WS_FUSED = 4096 + 524288 + 4096 + 16777216;  // flag|Wf|bf|aout

  if (ws_size >= WS_FUSED) {
    // ---- fused path: wo folded into conv; weights pre-converted; transpose inline ----
    u16*   Wf   = (u16*)((char*)d_ws + 4096);
    float* bfus = (float*)((char*)d_ws + 4096 + 524288);
    u16*   aout = (u16*)((char*)d_ws + 4096 + 524288 + 4096);
    u16*   Wqkv = aout;    // 768x256 bf16 (393KB) in aout region; dead before attn writes
    k_fuse_w<<<dim3(64,3), 256, 0, stream>>>((const u32*)x, wq, wkv, wo, wconv, bo, bconv,
                                             Wf, bfus, Wqkv, flag);
    // qkv projection straight from x (inline transpose), bf16 weights, XCD swizzle
    k_gemm_bt<0,1,1,1><<<dim3(256,6), 256, 0, stream>>>(x, 0, Wqkv, nullptr, 256, nullptr,
                                               qkv, 32768, 768, 256, 0.125f, 1.0f, flag);
    k_halo_attn<1><<<dim3(512,4), 256, 0, stream>>>(qkv, relh, relw, aout, 256, flag);
    k_gemm_bt<1,1,0,1><<<dim3(256,8), 256, 0, stream>>>(aout, 256, Wf, nullptr, 0, bfus,
                                               d_out, 32768, 1024, 256, 1.0f, 1.0f, flag);
  } else {
    // ---- fallback (r2 pipeline): separate transpose + wo-GEMM through y2 in ws ----
    u16* y2 = (u16*)((char*)d_ws + 4096);
    k_detect<<<1, 256, 0, stream>>>((const u32*)x, flag);
    k_transpose<<<dim3(64,4,8), 256, 0, stream>>>(x, xt, flag);
    k_gemm_bt<0,0,0,0><<<dim3(256,6), 256, 0, stream>>>(xt, 256, wq, wkv, 256, nullptr,
                                               qkv, 32768, 768, 256, 0.125f, 1.0f, flag);
    k_halo_attn<0><<<dim3(512,4), 256, 0, stream>>>(qkv, relh, relw, qkv, 768, flag);
    k_gemm_bt<0,0,0,0><<<dim3(256,2), 256, 0, stream>>>(qkv, 768, wo, nullptr, 0, bo,
                                               y2, 32768, 256, 256, 1.0f, 1.0f, flag);
    k_gemm_bt<1,0,0,0><<<dim3(256,8), 256, 0, stream>>>(y2, 256, wconv, nullptr, 0, bconv,
                                               d_out, 32768, 1024, 256, 1.0f, 1.0f, flag);
  }
}